// Round 8
// baseline (656.847 us; speedup 1.0000x reference)
//
#include <hip/hip_runtime.h>
#include <hip/hip_bf16.h>

typedef unsigned short u16;
typedef __attribute__((ext_vector_type(8))) short bf16x8;
typedef __attribute__((ext_vector_type(4))) float f32x4;
#define MFMA16(a,b,c) __builtin_amdgcn_mfma_f32_16x16x32_bf16(a,b,c,0,0,0)
#define VPAD 100000

__device__ __forceinline__ float sigf(float x){ return 1.0f/(1.0f + __expf(-x)); }
__device__ __forceinline__ float ftanh(float x){
    float ax = fabsf(x);
    float e = __expf(-2.f*ax);
    float r = (1.f - e) / (1.f + e);
    return copysignf(r, x);
}
__device__ __forceinline__ u16 f2b(float f){
    unsigned u = __float_as_uint(f);
    u += 0x7fffu + ((u >> 16) & 1u);
    return (u16)(u >> 16);
}
__device__ __forceinline__ unsigned int pk2(float x, float y){
    return ((unsigned)f2b(y) << 16) | (unsigned)f2b(x);
}
__device__ __forceinline__ float b2f(u16 u){
    return __uint_as_float(((unsigned int)u) << 16);
}
__device__ __forceinline__ uint4 pk8(float4 x, float4 y){
    uint4 o;
    o.x = pk2(x.x,x.y); o.y = pk2(x.z,x.w);
    o.z = pk2(y.x,y.y); o.w = pk2(y.z,y.w);
    return o;
}

// ---------------------------------------------------------------------------
// prep: weight preprocessing (no emb conversion).
//  p1W/p2W f32->bf16; qWih/qWhh live-row pack (n'=4d+gate); naW frag blob;
//  bias combine.
// ---------------------------------------------------------------------------
__global__ __launch_bounds__(256) void prep_kernel(
    const float* __restrict__ p1W, const float* __restrict__ p2W,
    const float* __restrict__ naW,
    const float* __restrict__ qWih, const float* __restrict__ qWhh,
    const float* __restrict__ qBih, const float* __restrict__ qBhh,
    u16* __restrict__ p1Wb, u16* __restrict__ p2Wb,
    u16* __restrict__ nawf, u16* __restrict__ WihS, u16* __restrict__ WhhS,
    float* __restrict__ bc)
{
    const long gid = (long)blockIdx.x * 256 + threadIdx.x;
    const long E0 = 131072;         // p1W float4 units
    const long E1 = E0 + 131072;    // p2W
    const long E2 = E1 + 131072;    // Wih pack (8 u16/thread)
    const long E3 = E2 + 131072;    // Whh pack
    const long E4 = E3 + 16384;     // naW frag pack
    const long E5 = E4 + 2048;      // bias comb
    if (gid < E0){
        float4 v = reinterpret_cast<const float4*>(p1W)[gid];
        uint2 s; s.x = pk2(v.x,v.y); s.y = pk2(v.z,v.w);
        reinterpret_cast<uint2*>(p1Wb)[gid] = s;
    } else if (gid < E1){
        long i = gid - E0;
        float4 v = reinterpret_cast<const float4*>(p2W)[i];
        uint2 s; s.x = pk2(v.x,v.y); s.y = pk2(v.z,v.w);
        reinterpret_cast<uint2*>(p2Wb)[i] = s;
    } else if (gid < E2){
        long j = gid - E1;
        int n = (int)(j >> 6), c8 = (int)(j & 63);
        int srow = (n & 3) * 1024 + (n >> 2);
        const float* sp = qWih + (size_t)srow * 512 + c8 * 8;
        float4 a = *reinterpret_cast<const float4*>(sp);
        float4 b = *reinterpret_cast<const float4*>(sp + 4);
        *reinterpret_cast<uint4*>(WihS + (size_t)n*512 + c8*8) = pk8(a,b);
    } else if (gid < E3){
        long j = gid - E2;
        int n = (int)(j >> 6), c8 = (int)(j & 63);
        int srow = (n & 3) * 1024 + (n >> 2);
        const float* sp = qWhh + (size_t)srow * 1024 + c8 * 8;
        float4 a = *reinterpret_cast<const float4*>(sp);
        float4 b = *reinterpret_cast<const float4*>(sp + 4);
        *reinterpret_cast<uint4*>(WhhS + (size_t)n*512 + c8*8) = pk8(a,b);
    } else if (gid < E4){
        long j = gid - E3;                 // 0..16383
        int f = (int)(j >> 6), lane = (int)(j & 63);
        int ks = f >> 4, ig = f & 15;
        int col = lane & 15, quad = lane >> 4;
        int n = ig*16 + col;
        int k0 = ks*32 + quad*8;
        const float* sp = naW + (size_t)n*512 + k0;
        float4 a = *reinterpret_cast<const float4*>(sp);
        float4 b = *reinterpret_cast<const float4*>(sp + 4);
        *reinterpret_cast<uint4*>(nawf + j*8) = pk8(a,b);
    } else if (gid < E5){
        int n = (int)(gid - E4);
        int row = (n & 3) * 1024 + (n >> 2);
        bc[n] = qBih[row] + qBhh[row];
    }
}

// ---------------------------------------------------------------------------
// Neighbor encoder v7: one block per (row, side) — grid 4102.
// One-shot gather (T14): both phases' ids are known upfront, so issue all 16
// global loads back-to-back (2x MLP, ONE latency exposure instead of two),
// write frg[0] (rel), frg[1] (ent) and the f32 entf stash in one phase, then
// a single barrier and 16 uninterrupted ksl MFMA steps (removes 3 barriers).
// LDS 64.6KB -> 2 blocks/CU (r6: occupancy in this range is time-neutral).
// Softmax parallelized over first 32 lanes (was serial t==0).
// ---------------------------------------------------------------------------
__global__ __launch_bounds__(256) void neighbor_v7(
    const int* __restrict__ qL, const int* __restrict__ qR,
    const int* __restrict__ sL, const int* __restrict__ sR,
    const float* __restrict__ emb,
    const u16* __restrict__ nawf,
    const float* __restrict__ naB, const float* __restrict__ nuW,
    const float* __restrict__ nuB,
    float* __restrict__ out, u16* __restrict__ out_bf)
{
    __shared__ __align__(16) u16 frg[2][16*512];  // 2 x 16KB (rel, ent)
    __shared__ __align__(16) float entf[32*256];  // f32 ent stash (32KB)
    __shared__ int relid[32];
    __shared__ int entid[32];
    __shared__ float logit[32];
    __shared__ float att[32];

    const int t = threadIdx.x;
    const int bx = blockIdx.x;     // 0..4101
    const int row = bx >> 1;       // 0..2050
    const int s = bx & 1;          // side: 0=L 1=R
    if (t < 64){
        int k = t >> 1, which = t & 1;
        const int* conn;
        if (row < 2048) conn = (s ? qR : qL) + (size_t)row * 60;
        else            conn = (s ? sR : sL) + (size_t)(row - 2048) * 60;
        int id = (k < 30) ? conn[k*2 + which] : VPAD;
        if (which) entid[k] = id; else relid[k] = id;
    }
    if (t >= 64 && t < 96) logit[t-64] = 0.f;
    __syncthreads();

    const int w = t >> 6, lane = t & 63;
    const int col = lane & 15, quad = lane >> 4;

    // decode gather unit (1024 units: 32 k-rows x 32 chunks)
    int gc[4], gk[4];
    #pragma unroll
    for (int i = 0; i < 4; i++){
        int idx = i*256 + t;
        gc[i] = idx & 31;            // 8-elem chunk within 256-elem row
        gk[i] = (idx >> 5) & 31;     // k-row 0..31
    }

    // issue ALL 16 loads first (max MLP), then consume
    float4 rx[4], ry[4], ex[4], ey[4];
    #pragma unroll
    for (int i = 0; i < 4; i++){
        const float* ptr = emb + (size_t)relid[gk[i]]*256 + gc[i]*8;
        rx[i] = *reinterpret_cast<const float4*>(ptr);
        ry[i] = *reinterpret_cast<const float4*>(ptr + 4);
    }
    #pragma unroll
    for (int i = 0; i < 4; i++){
        const float* ptr = emb + (size_t)entid[gk[i]]*256 + gc[i]*8;
        ex[i] = *reinterpret_cast<const float4*>(ptr);
        ey[i] = *reinterpret_cast<const float4*>(ptr + 4);
    }
    #pragma unroll
    for (int i = 0; i < 4; i++){
        int k = gk[i], c = gc[i], e0 = c*8;
        int ksl = e0 >> 5, q = (e0 >> 3) & 3;
        int mt = k >> 4, cl = k & 15;
        int ln = q*16 + cl;
        int fo = (((mt*8 + ksl)*64) + ln)*8;
        *reinterpret_cast<uint4*>(&frg[0][fo]) = pk8(rx[i], ry[i]);
        *reinterpret_cast<uint4*>(&frg[1][fo]) = pk8(ex[i], ey[i]);
        float* fd = entf + k*256 + e0;
        *reinterpret_cast<float4*>(fd)     = ex[i];
        *reinterpret_cast<float4*>(fd + 4) = ey[i];
    }
    __syncthreads();

    // MFMA: 16 ks steps, no intervening barriers (frg never rewritten)
    f32x4 acc[2][4] = {};
    #pragma unroll
    for (int p = 0; p < 2; p++){
        #pragma unroll
        for (int ksl = 0; ksl < 8; ksl++){
            bf16x8 a[2], b[4];
            #pragma unroll
            for (int u = 0; u < 2; u++)
                a[u] = *reinterpret_cast<const bf16x8*>(&frg[p][(((u*8 + ksl)*64) + lane)*8]);
            const int ks = p*8 + ksl;
            #pragma unroll
            for (int i = 0; i < 4; i++)
                b[i] = *reinterpret_cast<const bf16x8*>(nawf + ((size_t)(ks*16 + w*4 + i)*64 + lane)*8);
            #pragma unroll
            for (int i = 0; i < 4; i++)
                #pragma unroll
                for (int u = 0; u < 2; u++)
                    acc[u][i] = MFMA16(a[u], b[i], acc[u][i]);
        }
    }

    // logits
    float nu[4], nbv[4];
    #pragma unroll
    for (int i = 0; i < 4; i++){
        int n = (w*4 + i)*16 + col;
        nu[i] = nuW[n]; nbv[i] = naB[n];
    }
    #pragma unroll
    for (int u = 0; u < 2; u++){
        #pragma unroll
        for (int r = 0; r < 4; r++){
            int m = u*16 + quad*4 + r;
            float v = 0.f;
            #pragma unroll
            for (int i = 0; i < 4; i++)
                v += ftanh(acc[u][i][r] + nbv[i]) * nu[i];
            v += __shfl_xor(v, 1); v += __shfl_xor(v, 2);
            v += __shfl_xor(v, 4); v += __shfl_xor(v, 8);
            if (col == 0 && m < 30) atomicAdd(&logit[m], v);
        }
    }
    __syncthreads();

    // wave-parallel softmax over 30 logits (first 32 lanes)
    if (t < 32){
        const float nub = nuB[0];
        float L = (t < 30) ? (logit[t] + nub) : -1e30f;
        float mx = L;
        #pragma unroll
        for (int d = 1; d < 32; d <<= 1) mx = fmaxf(mx, __shfl_xor(mx, d));
        float e = (t < 30) ? __expf(L - mx) : 0.f;
        float sm = e;
        #pragma unroll
        for (int d = 1; d < 32; d <<= 1) sm += __shfl_xor(sm, d);
        if (t < 30) att[t] = e * (1.f / sm);
    }
    __syncthreads();

    // agg: thread t = column e (0..255); ent rows from LDS stash
    const int e = t;
    float agg = 0.f;
    #pragma unroll
    for (int k = 0; k < 30; k++)
        agg += att[k] * entf[k*256 + e];
    float r = ftanh(agg);
    size_t oi = (size_t)row*512 + s*256 + e;
    out[oi] = r;
    out_bf[oi] = f2b(r);
}

// ---------------------------------------------------------------------------
// gemm_tn: C[m,n] = act( A[m,:]·B[n,:] + bias[n] (+addD[m,n]) )
// A bf16 [M x lda], B bf16 [N x ldb]. 128x64 tile, 4 waves of 64x32.
// ---------------------------------------------------------------------------
__global__ __launch_bounds__(256) void gemm_tn(
    const u16* __restrict__ A, int lda,
    const u16* __restrict__ B, int ldb,
    const float* __restrict__ bias,
    const float* __restrict__ addD, int ldd,
    float* __restrict__ Cf, u16* __restrict__ Cbf, int ldc,
    int K, int relu)
{
    __shared__ __align__(16) u16 As[128][72];
    __shared__ __align__(16) u16 Bs[64][72];
    const int t = threadIdx.x;
    const int m0 = blockIdx.y * 128, n0 = blockIdx.x * 64;
    const int w = t >> 6, lane = t & 63;
    const int col = lane & 15, quad = lane >> 4;
    const int wm = (w & 1) * 64, wn = (w >> 1) * 32;

    int arow[4], aseg[4], brow[2], bseg[2];
    #pragma unroll
    for (int i = 0; i < 4; i++){
        int idx = i*256 + t; arow[i] = idx >> 3; aseg[i] = (idx & 7) * 8;
    }
    #pragma unroll
    for (int i = 0; i < 2; i++){
        int idx = i*256 + t; brow[i] = idx >> 3; bseg[i] = (idx & 7) * 8;
    }

    f32x4 acc[4][2] = {};

    const int KC = K >> 6;
    for (int kc = 0; kc < KC; kc++){
        uint4 av[4], bv[2];
        #pragma unroll
        for (int i = 0; i < 4; i++)
            av[i] = *reinterpret_cast<const uint4*>(A + (size_t)(m0 + arow[i])*lda + kc*64 + aseg[i]);
        #pragma unroll
        for (int i = 0; i < 2; i++)
            bv[i] = *reinterpret_cast<const uint4*>(B + (size_t)(n0 + brow[i])*ldb + kc*64 + bseg[i]);
        __syncthreads();
        #pragma unroll
        for (int i = 0; i < 4; i++)
            *reinterpret_cast<uint4*>(&As[arow[i]][aseg[i]]) = av[i];
        #pragma unroll
        for (int i = 0; i < 2; i++)
            *reinterpret_cast<uint4*>(&Bs[brow[i]][bseg[i]]) = bv[i];
        __syncthreads();
        #pragma unroll
        for (int ks = 0; ks < 2; ks++){
            const int k0 = ks*32 + quad*8;
            bf16x8 af[4], bf[2];
            #pragma unroll
            for (int i = 0; i < 4; i++) af[i] = *reinterpret_cast<const bf16x8*>(&As[wm + i*16 + col][k0]);
            #pragma unroll
            for (int j = 0; j < 2; j++) bf[j] = *reinterpret_cast<const bf16x8*>(&Bs[wn + j*16 + col][k0]);
            #pragma unroll
            for (int i = 0; i < 4; i++)
                #pragma unroll
                for (int j = 0; j < 2; j++)
                    acc[i][j] = MFMA16(af[i], bf[j], acc[i][j]);
        }
    }

    #pragma unroll
    for (int j = 0; j < 2; j++){
        int n = n0 + wn + j*16 + col;
        float bj = bias[n];
        #pragma unroll
        for (int i = 0; i < 4; i++){
            #pragma unroll
            for (int r = 0; r < 4; r++){
                int m = m0 + wm + i*16 + quad*4 + r;
                float v = acc[i][j][r] + bj;
                if (addD) v += addD[(size_t)m*ldd + n];
                if (relu) v = fmaxf(v, 0.f);
                if (Cf)  Cf[(size_t)m*ldc + n] = v;
                if (Cbf) Cbf[(size_t)m*ldc + n] = f2b(v);
            }
        }
    }
}

// ---------------------------------------------------------------------------
// LayerNorm(Z + X), ddof=1, eps on sigma. One wave per row; 2051 rows.
// ---------------------------------------------------------------------------
__global__ __launch_bounds__(256) void ln_kernel(
    const float* __restrict__ Z, const float* __restrict__ X, int N, int nquery,
    const float* __restrict__ lnA, const float* __restrict__ lnB,
    float* __restrict__ Y, u16* __restrict__ Ybf, float* __restrict__ Ycopy)
{
    const int wv = threadIdx.x >> 6, lane = threadIdx.x & 63;
    const int row = blockIdx.x * 4 + wv;
    if (row >= N) return;
    const float* z = Z + (size_t)row * 512;
    const float* x = X + (size_t)row * 512;
    float v[8];
    float s = 0.f, ss = 0.f;
    {
        float4 z0 = *reinterpret_cast<const float4*>(z + lane*8);
        float4 z1 = *reinterpret_cast<const float4*>(z + lane*8 + 4);
        float4 x0 = *reinterpret_cast<const float4*>(x + lane*8);
        float4 x1 = *reinterpret_cast<const float4*>(x + lane*8 + 4);
        v[0]=z0.x+x0.x; v[1]=z0.y+x0.y; v[2]=z0.z+x0.z; v[3]=z0.w+x0.w;
        v[4]=z1.x+x1.x; v[5]=z1.y+x1.y; v[6]=z1.z+x1.z; v[7]=z1.w+x1.w;
    }
    #pragma unroll
    for (int u = 0; u < 8; u++){ s += v[u]; ss += v[u]*v[u]; }
    #pragma unroll
    for (int d = 1; d < 64; d <<= 1){
        s  += __shfl_xor(s, d);
        ss += __shfl_xor(ss, d);
    }
    float mu  = s * (1.f/512.f);
    float var = (ss - 512.f*mu*mu) * (1.f/511.f);
    float sd  = sqrtf(fmaxf(var, 0.f));
    float inv = 1.f / (sd + 1e-3f);
    float o[8];
    #pragma unroll
    for (int u = 0; u < 8; u++){
        int e = lane*8 + u;
        o[u] = (v[u] - mu) * inv * lnA[e] + lnB[e];
    }
    float* yr = Y + (size_t)row*512 + lane*8;
    *reinterpret_cast<float4*>(yr)     = make_float4(o[0],o[1],o[2],o[3]);
    *reinterpret_cast<float4*>(yr + 4) = make_float4(o[4],o[5],o[6],o[7]);
    if (row < nquery){
        uint4 p;
        p.x = pk2(o[0],o[1]); p.y = pk2(o[2],o[3]);
        p.z = pk2(o[4],o[5]); p.w = pk2(o[6],o[7]);
        *reinterpret_cast<uint4*>(Ybf + (size_t)row*512 + lane*8) = p;
        float* cr = Ycopy + (size_t)row*512 + lane*8;
        *reinterpret_cast<float4*>(cr)     = make_float4(o[0],o[1],o[2],o[3]);
        *reinterpret_cast<float4*>(cr + 4) = make_float4(o[4],o[5],o[6],o[7]);
    }
}

// ---------------------------------------------------------------------------
// Small LSTM cell (D=512, batch=1): 128 blocks x 4 d, one wave per d
// ---------------------------------------------------------------------------
__global__ __launch_bounds__(256) void lstm_small(
    const float* __restrict__ x, const float* __restrict__ hin,
    float* __restrict__ c,
    const float* __restrict__ Wih, const float* __restrict__ Whh,
    const float* __restrict__ bih, const float* __restrict__ bhh,
    float* __restrict__ hout)
{
    __shared__ float xs[512], hs[512];
    __shared__ float gbuf[4][4];
    const int t = threadIdx.x;
    for (int i = t; i < 512; i += 256){ xs[i] = x[i]; hs[i] = hin[i]; }
    __syncthreads();

    const int wd = t >> 6;
    const int lane = t & 63;
    const int g = lane >> 4, p = lane & 15;
    const int d = blockIdx.x*4 + wd;
    const int j = g*512 + d;
    const float4* wi = reinterpret_cast<const float4*>(Wih + (size_t)j*512) + p*8;
    const float4* wh = reinterpret_cast<const float4*>(Whh + (size_t)j*512) + p*8;
    float acc = 0.f;
    #pragma unroll
    for (int q = 0; q < 8; q++){
        float4 wv = wi[q];
        const int kb = p*32 + q*4;
        acc += xs[kb]*wv.x + xs[kb+1]*wv.y + xs[kb+2]*wv.z + xs[kb+3]*wv.w;
        float4 vv = wh[q];
        acc += hs[kb]*vv.x + hs[kb+1]*vv.y + hs[kb+2]*vv.z + hs[kb+3]*vv.w;
    }
    acc += __shfl_xor(acc, 1); acc += __shfl_xor(acc, 2);
    acc += __shfl_xor(acc, 4); acc += __shfl_xor(acc, 8);
    if (p == 0) gbuf[wd][g] = acc + bih[j] + bhh[j];
    __syncthreads();
    if (t < 4){
        int dd = blockIdx.x*4 + t;
        float iv = gbuf[t][0], fv = gbuf[t][1], gv = gbuf[t][2], ov = gbuf[t][3];
        float cn = sigf(fv)*c[dd] + sigf(iv)*ftanh(gv);
        float hn = sigf(ov)*ftanh(cn);
        c[dd] = cn; hout[dd] = hn;
    }
}

// ---------------------------------------------------------------------------
// ae_loss + sge_enc (singleton softmax == 1)
// ---------------------------------------------------------------------------
__global__ __launch_bounds__(256) void finalize_kernel(
    const float* __restrict__ sg, const float* __restrict__ enc,
    const float* __restrict__ dec, float* __restrict__ sgeenc,
    float* __restrict__ outp)
{
    __shared__ float red[4];
    const int t = threadIdx.x;
    float s = 0.f;
    for (int i = t; i < 1536; i += 256){ float d = sg[i] - dec[i]; s += d*d; }
    s += __shfl_xor(s,1); s += __shfl_xor(s,2); s += __shfl_xor(s,4);
    s += __shfl_xor(s,8); s += __shfl_xor(s,16); s += __shfl_xor(s,32);
    if ((t & 63) == 0) red[t>>6] = s;
    __syncthreads();
    if (t == 0){
        float tot = (red[0]+red[1]+red[2]+red[3]) * (1.f/1536.f);
        outp[2048] = tot;
    }
    for (int d = t; d < 512; d += 256){
        float v = sg[d] + enc[d] + sg[512+d] + enc[512+d] + sg[1024+d] + enc[1024+d];
        sgeenc[d] = v;
        outp[2049 + d] = v;
    }
}

// ---------------------------------------------------------------------------
// wvec[n'] = sum_j sge[j] * qWhh[(n'&3)*1024 + (n'>>2), 512+j]
// ---------------------------------------------------------------------------
__global__ __launch_bounds__(256) void wvec_kernel(
    const float* __restrict__ qWhh, const float* __restrict__ sge,
    float* __restrict__ wvec)
{
    __shared__ float ss[512];
    const int t = threadIdx.x;
    for (int i = t; i < 512; i += 256) ss[i] = sge[i];
    __syncthreads();
    const int n = blockIdx.x * 256 + t;
    const int row = (n & 3) * 1024 + (n >> 2);
    const float4* w = reinterpret_cast<const float4*>(qWhh + (size_t)row*1024 + 512);
    float acc = 0.f;
    for (int kc = 0; kc < 128; kc++){
        float4 wv = w[kc];
        const int kb = kc*4;
        acc += ss[kb]*wv.x + ss[kb+1]*wv.y + ss[kb+2]*wv.z + ss[kb+3]*wv.w;
    }
    wvec[n] = acc;
}

// ---------------------------------------------------------------------------
// Gate math on packed G: g4 = (i,f,g,o) at G[b*2048 + 4d]
// first!=0: treat c as 0 (base step) — removes the cb memset + zero-read.
// ---------------------------------------------------------------------------
__global__ __launch_bounds__(256) void gate_kernel(
    const float* __restrict__ G, const float* __restrict__ qg,
    float* __restrict__ c, u16* __restrict__ h_bf, int first)
{
    const int idx = blockIdx.x * 256 + threadIdx.x;
    const int b = idx >> 9, d = idx & 511;
    float4 g4 = *reinterpret_cast<const float4*>(G + (size_t)b*2048 + d*4);
    float c0 = first ? 0.f : c[idx];
    float cn = sigf(g4.y)*c0 + sigf(g4.x)*ftanh(g4.z);
    float hn = qg[idx] + sigf(g4.w)*ftanh(cn);
    c[idx] = cn; h_bf[idx] = f2b(hn);
}

// ---------------------------------------------------------------------------
// matching_scores[b] = dot(h[b], sge_enc)
// ---------------------------------------------------------------------------
__global__ __launch_bounds__(256) void scores_kernel(
    const u16* __restrict__ h, const float* __restrict__ sge,
    float* __restrict__ out)
{
    const int wave = threadIdx.x >> 6, lane = threadIdx.x & 63;
    const int row = blockIdx.x * 4 + wave;
    const u16* hr = h + (size_t)row * 512;
    float s = 0.f;
    for (int i = lane; i < 512; i += 64) s += b2f(hr[i]) * sge[i];
    s += __shfl_xor(s,1); s += __shfl_xor(s,2); s += __shfl_xor(s,4);
    s += __shfl_xor(s,8); s += __shfl_xor(s,16); s += __shfl_xor(s,32);
    if (lane == 0) out[row] = s;
}

// ---------------------------------------------------------------------------
extern "C" void kernel_launch(void* const* d_in, const int* in_sizes, int n_in,
                              void* d_out, int out_size, void* d_ws, size_t ws_size,
                              hipStream_t stream)
{
    (void)in_sizes; (void)n_in; (void)out_size; (void)ws_size;

    const int* qlc = (const int*)d_in[2];
    const int* qrc = (const int*)d_in[4];
    const int* slc = (const int*)d_in[6];
    const int* src = (const int*)d_in[8];
    const float* emb = (const float*)d_in[10];
    const float* naW = (const float*)d_in[11];
    const float* naB = (const float*)d_in[12];
    const float* nuW = (const float*)d_in[13];
    const float* nuB = (const float*)d_in[14];
    const float* p1W = (const float*)d_in[15], *p1b = (const float*)d_in[16];
    const float* p2W = (const float*)d_in[17], *p2b = (const float*)d_in[18];
    const float* lnA = (const float*)d_in[19], *lnB = (const float*)d_in[20];
    const float* eWih = (const float*)d_in[21], *eWhh = (const float*)d_in[22];
    const float* eBih = (const float*)d_in[23], *eBhh = (const float*)d_in[24];
    const float* dWih = (const float*)d_in[25], *dWhh = (const float*)d_in[26];
    const float* dBih = (const float*)d_in[27], *dBhh = (const float*)d_in[28];
    const float* qWih = (const float*)d_in[33], *qWhh = (const float*)d_in[34];
    const float* qBih = (const float*)d_in[35], *qBhh = (const float*)d_in[36];
    float* out = (float*)d_out;

    float* w = (float*)d_ws;
    size_t off = 0;
    auto alloc = [&](size_t nelem){ float* p = w + off; off += nelem; return p; };
    float* qn    = alloc(2176ull*512);   // neighbor f32 (2051 rows used)
    float* qg    = alloc(2176ull*512);   // query_g f32 (+ sg rows 2048..2050)
    float* enc   = alloc(1536);
    float* dec   = alloc(1536);
    float* zc    = alloc(1024);
    float* sgee  = alloc(512);
    float* wv    = alloc(2048);
    float* bc    = alloc(2048);
    float* nawfF = alloc(65536);         // 131072 u16 frag-packed naW
    float* base  = alloc(2048ull*2048);  // + Zq, qn_bf aliases
    float* G     = alloc(2048ull*2048);  // + Hq_bf, qg_bf aliases
    float* cb    = alloc(2048ull*512);
    float* hbfF  = alloc(524288);        // h bf16
    float* p1WbF = alloc(262144);
    float* p2WbF = alloc(262144);
    float* WihSF = alloc(524288);
    float* WhhSF = alloc(524288);

    u16* nawf   = (u16*)nawfF;
    u16* p1Wb   = (u16*)p1WbF;
    u16* p2Wb   = (u16*)p2WbF;
    u16* WihSel = (u16*)WihSF;
    u16* WhhSel = (u16*)WhhSF;
    u16* h_bf   = (u16*)hbfF;
    float* Zq   = base;                       // 2176x512 f32
    u16* qn_bf  = (u16*)(base + 2097152);     // 2176x512 u16
    u16* Hq_bf  = (u16*)G;                    // 2176x1024 u16
    u16* qg_bf  = (u16*)(G + 2097152);        // 2176x512 u16 (2048 used)
    float* sg   = qg + 2048ull*512;
    float* zbuf = zc;
    float* cst  = zc + 512;

    hipMemsetAsync(zc, 0, 1024*sizeof(float), stream);

    // weight preprocessing (no emb conversion)
    prep_kernel<<<2120, 256, 0, stream>>>(p1W, p2W, naW, qWih, qWhh, qBih, qBhh,
                                          p1Wb, p2Wb, nawf, WihSel, WhhSel, bc);

    // neighbor encoder: (row, side) blocks — 2051 rows x 2 sides
    neighbor_v7<<<4102, 256, 0, stream>>>(qlc, qrc, slc, src, emb,
                                          nawf, naB, nuW, nuB, qn, qn_bf);

    // support encoder fused over 2051 rows: H=relu(X@p1W^T+b); Z=H@p2W^T+b; LN
    gemm_tn<<<dim3(16,17), 256, 0, stream>>>(qn_bf, 512, p1Wb, 512, p1b, nullptr, 0,
                                             nullptr, Hq_bf, 1024, 512, 1);
    gemm_tn<<<dim3(8,17), 256, 0, stream>>>(Hq_bf, 1024, p2Wb, 1024, p2b, nullptr, 0,
                                            Zq, nullptr, 512, 1024, 0);
    ln_kernel<<<513, 256, 0, stream>>>(Zq, qn, 2051, 2048, lnA, lnB, qg, qg_bf, out + 2561);

    // set autoencoder
    lstm_small<<<128, 256, 0, stream>>>(sg,        zbuf,      cst, eWih, eWhh, eBih, eBhh, enc);
    lstm_small<<<128, 256, 0, stream>>>(sg + 512,  enc,       cst, eWih, eWhh, eBih, eBhh, enc + 512);
    lstm_small<<<128, 256, 0, stream>>>(sg + 1024, enc + 512, cst, eWih, eWhh, eBih, eBhh, enc + 1024);
    lstm_small<<<128, 256, 0, stream>>>(enc + 1024, enc + 1024, cst, dWih, dWhh, dBih, dBhh, dec);
    lstm_small<<<128, 256, 0, stream>>>(dec,        dec,        cst, dWih, dWhh, dBih, dBhh, dec + 512);
    lstm_small<<<128, 256, 0, stream>>>(dec + 512,  dec + 512,  cst, dWih, dWhh, dBih, dBhh, dec + 1024);

    finalize_kernel<<<1, 256, 0, stream>>>(sg, enc, dec, sgee, out);
    wvec_kernel<<<8, 256, 0, stream>>>(qWhh, sgee, wv);

    // query encoder: base = qg@WihSel^T + bc; 4 steps (live half only)
    gemm_tn<<<dim3(32,16), 256, 0, stream>>>(qg_bf, 512, WihSel, 512, bc, nullptr, 0,
                                             base, nullptr, 2048, 512, 0);
    gate_kernel<<<4096, 256, 0, stream>>>(base, qg, cb, h_bf, 1);
    for (int s = 0; s < 3; s++){
        gemm_tn<<<dim3(32,16), 256, 0, stream>>>(h_bf, 512, WhhSel, 512, wv, base, 2048,
                                                 G, nullptr, 2048, 512, 0);
        gate_kernel<<<4096, 256, 0, stream>>>(G, qg, cb, h_bf, 0);
    }

    scores_kernel<<<512, 256, 0, stream>>>(h_bf, sgee, out);
}

// Round 9
// 631.943 us; speedup vs baseline: 1.0394x; 1.0394x over previous
//
#include <hip/hip_runtime.h>
#include <hip/hip_bf16.h>

typedef unsigned short u16;
typedef __attribute__((ext_vector_type(8))) short bf16x8;
typedef __attribute__((ext_vector_type(4))) float f32x4;
#define MFMA16(a,b,c) __builtin_amdgcn_mfma_f32_16x16x32_bf16(a,b,c,0,0,0)
#define VPAD 100000

__device__ __forceinline__ float sigf(float x){ return 1.0f/(1.0f + __expf(-x)); }
__device__ __forceinline__ float ftanh(float x){
    float ax = fabsf(x);
    float e = __expf(-2.f*ax);
    float r = (1.f - e) / (1.f + e);
    return copysignf(r, x);
}
__device__ __forceinline__ u16 f2b(float f){
    unsigned u = __float_as_uint(f);
    u += 0x7fffu + ((u >> 16) & 1u);
    return (u16)(u >> 16);
}
__device__ __forceinline__ unsigned int pk2(float x, float y){
    return ((unsigned)f2b(y) << 16) | (unsigned)f2b(x);
}
__device__ __forceinline__ float b2f(u16 u){
    return __uint_as_float(((unsigned int)u) << 16);
}
__device__ __forceinline__ uint4 pk8(float4 x, float4 y){
    uint4 o;
    o.x = pk2(x.x,x.y); o.y = pk2(x.z,x.w);
    o.z = pk2(y.x,y.y); o.w = pk2(y.z,y.w);
    return o;
}

// ---------------------------------------------------------------------------
// prep: weight preprocessing + zc zero-init (memset folded in).
//  p1W/p2W f32->bf16; qWih/qWhh live-row pack (n'=4d+gate); naW frag blob;
//  bias combine; zc[0..1023] = 0.
// ---------------------------------------------------------------------------
__global__ __launch_bounds__(256) void prep_kernel(
    const float* __restrict__ p1W, const float* __restrict__ p2W,
    const float* __restrict__ naW,
    const float* __restrict__ qWih, const float* __restrict__ qWhh,
    const float* __restrict__ qBih, const float* __restrict__ qBhh,
    u16* __restrict__ p1Wb, u16* __restrict__ p2Wb,
    u16* __restrict__ nawf, u16* __restrict__ WihS, u16* __restrict__ WhhS,
    float* __restrict__ bc, float* __restrict__ zc)
{
    const long gid = (long)blockIdx.x * 256 + threadIdx.x;
    const long E0 = 131072;         // p1W float4 units
    const long E1 = E0 + 131072;    // p2W
    const long E2 = E1 + 131072;    // Wih pack (8 u16/thread)
    const long E3 = E2 + 131072;    // Whh pack
    const long E4 = E3 + 16384;     // naW frag pack
    const long E5 = E4 + 2048;      // bias comb
    const long E6 = E5 + 1024;      // zc zero
    if (gid < E0){
        float4 v = reinterpret_cast<const float4*>(p1W)[gid];
        uint2 s; s.x = pk2(v.x,v.y); s.y = pk2(v.z,v.w);
        reinterpret_cast<uint2*>(p1Wb)[gid] = s;
    } else if (gid < E1){
        long i = gid - E0;
        float4 v = reinterpret_cast<const float4*>(p2W)[i];
        uint2 s; s.x = pk2(v.x,v.y); s.y = pk2(v.z,v.w);
        reinterpret_cast<uint2*>(p2Wb)[i] = s;
    } else if (gid < E2){
        long j = gid - E1;
        int n = (int)(j >> 6), c8 = (int)(j & 63);
        int srow = (n & 3) * 1024 + (n >> 2);
        const float* sp = qWih + (size_t)srow * 512 + c8 * 8;
        float4 a = *reinterpret_cast<const float4*>(sp);
        float4 b = *reinterpret_cast<const float4*>(sp + 4);
        *reinterpret_cast<uint4*>(WihS + (size_t)n*512 + c8*8) = pk8(a,b);
    } else if (gid < E3){
        long j = gid - E2;
        int n = (int)(j >> 6), c8 = (int)(j & 63);
        int srow = (n & 3) * 1024 + (n >> 2);
        const float* sp = qWhh + (size_t)srow * 1024 + c8 * 8;
        float4 a = *reinterpret_cast<const float4*>(sp);
        float4 b = *reinterpret_cast<const float4*>(sp + 4);
        *reinterpret_cast<uint4*>(WhhS + (size_t)n*512 + c8*8) = pk8(a,b);
    } else if (gid < E4){
        long j = gid - E3;                 // 0..16383
        int f = (int)(j >> 6), lane = (int)(j & 63);
        int ks = f >> 4, ig = f & 15;
        int col = lane & 15, quad = lane >> 4;
        int n = ig*16 + col;
        int k0 = ks*32 + quad*8;
        const float* sp = naW + (size_t)n*512 + k0;
        float4 a = *reinterpret_cast<const float4*>(sp);
        float4 b = *reinterpret_cast<const float4*>(sp + 4);
        *reinterpret_cast<uint4*>(nawf + j*8) = pk8(a,b);
    } else if (gid < E5){
        int n = (int)(gid - E4);
        int row = (n & 3) * 1024 + (n >> 2);
        bc[n] = qBih[row] + qBhh[row];
    } else if (gid < E6){
        zc[gid - E5] = 0.f;
    }
}

// ---------------------------------------------------------------------------
// Neighbor encoder v6 (CHAMPION, 119us): one block per (row, side), grid 4102.
// Side-split + ent f32 LDS stash: phase p=1 also copies the gathered f32 ent
// rows into LDS; agg reads LDS instead of re-gathering from global.
// Ledger: v4=138 v5=139 v6=119 v7=145. LDS 49.7KB -> 3 blocks/CU; occupancy
// 21% hurts (v7), 31-74% is time-neutral (v5/v6). FETCH ~123MB = compulsory.
// ---------------------------------------------------------------------------
__global__ __launch_bounds__(256, 3) void neighbor_v6(
    const int* __restrict__ qL, const int* __restrict__ qR,
    const int* __restrict__ sL, const int* __restrict__ sR,
    const float* __restrict__ emb,
    const u16* __restrict__ nawf,
    const float* __restrict__ naB, const float* __restrict__ nuW,
    const float* __restrict__ nuB,
    float* __restrict__ out, u16* __restrict__ out_bf)
{
    __shared__ __align__(16) u16 frg[16*512];     // 16 frags x 1KB
    __shared__ __align__(16) float entf[32*256];  // f32 ent stash (32KB)
    __shared__ int relid[32];
    __shared__ int entid[32];
    __shared__ float logit[32];
    __shared__ float att[32];

    const int t = threadIdx.x;
    const int bx = blockIdx.x;     // 0..4101
    const int row = bx >> 1;       // 0..2050
    const int s = bx & 1;          // side: 0=L 1=R
    if (t < 64){
        int k = t >> 1, which = t & 1;
        const int* conn;
        if (row < 2048) conn = (s ? qR : qL) + (size_t)row * 60;
        else            conn = (s ? sR : sL) + (size_t)(row - 2048) * 60;
        int id = (k < 30) ? conn[k*2 + which] : VPAD;
        if (which) entid[k] = id; else relid[k] = id;
    }
    if (t >= 64 && t < 96) logit[t-64] = 0.f;
    __syncthreads();

    const int w = t >> 6, lane = t & 63;
    const int col = lane & 15, quad = lane >> 4;

    // decode gather unit (constant per thread across phases): 1024 units
    int gc[4], gk[4];
    #pragma unroll
    for (int i = 0; i < 4; i++){
        int idx = i*256 + t;
        gc[i] = idx & 31;            // 8-elem chunk within 256-elem half
        gk[i] = (idx >> 5) & 31;     // row 0..31
    }

    f32x4 acc[2][4] = {};

    #pragma unroll
    for (int p = 0; p < 2; p++){
        // gather phase p (p=0: rel, p=1: ent)
        #pragma unroll
        for (int i = 0; i < 4; i++){
            int k = gk[i], c = gc[i];
            int e0 = c*8;
            int id = p ? entid[k] : relid[k];
            const float* ptr = emb + (size_t)id*256 + e0;
            float4 x = *reinterpret_cast<const float4*>(ptr);
            float4 y = *reinterpret_cast<const float4*>(ptr + 4);
            int ksl = e0 >> 5, q = (e0 >> 3) & 3;
            int mt = k >> 4, cl = k & 15;
            int ln = q*16 + cl;
            u16* dst = frg + (((mt*8 + ksl)*64) + ln)*8;
            *reinterpret_cast<uint4*>(dst) = pk8(x, y);
            if (p){
                float* fd = entf + k*256 + e0;
                *reinterpret_cast<float4*>(fd)     = x;
                *reinterpret_cast<float4*>(fd + 4) = y;
            }
        }
        __syncthreads();

        // MFMA phase: 8 local ks steps
        #pragma unroll
        for (int ksl = 0; ksl < 8; ksl++){
            bf16x8 a[2], b[4];
            #pragma unroll
            for (int u = 0; u < 2; u++)
                a[u] = *reinterpret_cast<const bf16x8*>(frg + (((u*8 + ksl)*64) + lane)*8);
            const int ks = p*8 + ksl;
            #pragma unroll
            for (int i = 0; i < 4; i++)
                b[i] = *reinterpret_cast<const bf16x8*>(nawf + ((size_t)(ks*16 + w*4 + i)*64 + lane)*8);
            #pragma unroll
            for (int i = 0; i < 4; i++)
                #pragma unroll
                for (int u = 0; u < 2; u++)
                    acc[u][i] = MFMA16(a[u], b[i], acc[u][i]);
        }
        __syncthreads();
    }

    // logits
    float nu[4], nbv[4];
    #pragma unroll
    for (int i = 0; i < 4; i++){
        int n = (w*4 + i)*16 + col;
        nu[i] = nuW[n]; nbv[i] = naB[n];
    }
    #pragma unroll
    for (int u = 0; u < 2; u++){
        #pragma unroll
        for (int r = 0; r < 4; r++){
            int m = u*16 + quad*4 + r;
            float v = 0.f;
            #pragma unroll
            for (int i = 0; i < 4; i++)
                v += ftanh(acc[u][i][r] + nbv[i]) * nu[i];
            v += __shfl_xor(v, 1); v += __shfl_xor(v, 2);
            v += __shfl_xor(v, 4); v += __shfl_xor(v, 8);
            if (col == 0 && m < 30) atomicAdd(&logit[m], v);
        }
    }
    __syncthreads();

    if (t == 0){
        const float nub = nuB[0];
        float mx = -1e30f;
        float lg[30];
        #pragma unroll
        for (int k = 0; k < 30; k++){
            float L = logit[k] + nub;
            lg[k] = L; mx = fmaxf(mx, L);
        }
        float sm = 0.f;
        #pragma unroll
        for (int k = 0; k < 30; k++){ float e = __expf(lg[k]-mx); att[k] = e; sm += e; }
        float inv = 1.f / sm;
        #pragma unroll
        for (int k = 0; k < 30; k++) att[k] *= inv;
    }
    __syncthreads();

    // agg: thread t = column e (0..255); ent rows from LDS stash (bit-exact)
    const int e = t;
    float agg = 0.f;
    #pragma unroll
    for (int k = 0; k < 30; k++)
        agg += att[k] * entf[k*256 + e];
    float r = ftanh(agg);
    size_t oi = (size_t)row*512 + s*256 + e;
    out[oi] = r;
    out_bf[oi] = f2b(r);
}

// ---------------------------------------------------------------------------
// gemm_tn: C[m,n] = act( A[m,:]·B[n,:] + bias[n] (+addD[m,n]) )
// A bf16 [M x lda], B bf16 [N x ldb]. 128x64 tile, 4 waves of 64x32.
// ---------------------------------------------------------------------------
__global__ __launch_bounds__(256) void gemm_tn(
    const u16* __restrict__ A, int lda,
    const u16* __restrict__ B, int ldb,
    const float* __restrict__ bias,
    const float* __restrict__ addD, int ldd,
    float* __restrict__ Cf, u16* __restrict__ Cbf, int ldc,
    int K, int relu)
{
    __shared__ __align__(16) u16 As[128][72];
    __shared__ __align__(16) u16 Bs[64][72];
    const int t = threadIdx.x;
    const int m0 = blockIdx.y * 128, n0 = blockIdx.x * 64;
    const int w = t >> 6, lane = t & 63;
    const int col = lane & 15, quad = lane >> 4;
    const int wm = (w & 1) * 64, wn = (w >> 1) * 32;

    int arow[4], aseg[4], brow[2], bseg[2];
    #pragma unroll
    for (int i = 0; i < 4; i++){
        int idx = i*256 + t; arow[i] = idx >> 3; aseg[i] = (idx & 7) * 8;
    }
    #pragma unroll
    for (int i = 0; i < 2; i++){
        int idx = i*256 + t; brow[i] = idx >> 3; bseg[i] = (idx & 7) * 8;
    }

    f32x4 acc[4][2] = {};

    const int KC = K >> 6;
    for (int kc = 0; kc < KC; kc++){
        uint4 av[4], bv[2];
        #pragma unroll
        for (int i = 0; i < 4; i++)
            av[i] = *reinterpret_cast<const uint4*>(A + (size_t)(m0 + arow[i])*lda + kc*64 + aseg[i]);
        #pragma unroll
        for (int i = 0; i < 2; i++)
            bv[i] = *reinterpret_cast<const uint4*>(B + (size_t)(n0 + brow[i])*ldb + kc*64 + bseg[i]);
        __syncthreads();
        #pragma unroll
        for (int i = 0; i < 4; i++)
            *reinterpret_cast<uint4*>(&As[arow[i]][aseg[i]]) = av[i];
        #pragma unroll
        for (int i = 0; i < 2; i++)
            *reinterpret_cast<uint4*>(&Bs[brow[i]][bseg[i]]) = bv[i];
        __syncthreads();
        #pragma unroll
        for (int ks = 0; ks < 2; ks++){
            const int k0 = ks*32 + quad*8;
            bf16x8 af[4], bf[2];
            #pragma unroll
            for (int i = 0; i < 4; i++) af[i] = *reinterpret_cast<const bf16x8*>(&As[wm + i*16 + col][k0]);
            #pragma unroll
            for (int j = 0; j < 2; j++) bf[j] = *reinterpret_cast<const bf16x8*>(&Bs[wn + j*16 + col][k0]);
            #pragma unroll
            for (int i = 0; i < 4; i++)
                #pragma unroll
                for (int j = 0; j < 2; j++)
                    acc[i][j] = MFMA16(af[i], bf[j], acc[i][j]);
        }
    }

    #pragma unroll
    for (int j = 0; j < 2; j++){
        int n = n0 + wn + j*16 + col;
        float bj = bias[n];
        #pragma unroll
        for (int i = 0; i < 4; i++){
            #pragma unroll
            for (int r = 0; r < 4; r++){
                int m = m0 + wm + i*16 + quad*4 + r;
                float v = acc[i][j][r] + bj;
                if (addD) v += addD[(size_t)m*ldd + n];
                if (relu) v = fmaxf(v, 0.f);
                if (Cf)  Cf[(size_t)m*ldc + n] = v;
                if (Cbf) Cbf[(size_t)m*ldc + n] = f2b(v);
            }
        }
    }
}

// ---------------------------------------------------------------------------
// LayerNorm(Z + X), ddof=1, eps on sigma. One wave per row; 2051 rows.
// ---------------------------------------------------------------------------
__global__ __launch_bounds__(256) void ln_kernel(
    const float* __restrict__ Z, const float* __restrict__ X, int N, int nquery,
    const float* __restrict__ lnA, const float* __restrict__ lnB,
    float* __restrict__ Y, u16* __restrict__ Ybf, float* __restrict__ Ycopy)
{
    const int wv = threadIdx.x >> 6, lane = threadIdx.x & 63;
    const int row = blockIdx.x * 4 + wv;
    if (row >= N) return;
    const float* z = Z + (size_t)row * 512;
    const float* x = X + (size_t)row * 512;
    float v[8];
    float s = 0.f, ss = 0.f;
    {
        float4 z0 = *reinterpret_cast<const float4*>(z + lane*8);
        float4 z1 = *reinterpret_cast<const float4*>(z + lane*8 + 4);
        float4 x0 = *reinterpret_cast<const float4*>(x + lane*8);
        float4 x1 = *reinterpret_cast<const float4*>(x + lane*8 + 4);
        v[0]=z0.x+x0.x; v[1]=z0.y+x0.y; v[2]=z0.z+x0.z; v[3]=z0.w+x0.w;
        v[4]=z1.x+x1.x; v[5]=z1.y+x1.y; v[6]=z1.z+x1.z; v[7]=z1.w+x1.w;
    }
    #pragma unroll
    for (int u = 0; u < 8; u++){ s += v[u]; ss += v[u]*v[u]; }
    #pragma unroll
    for (int d = 1; d < 64; d <<= 1){
        s  += __shfl_xor(s, d);
        ss += __shfl_xor(ss, d);
    }
    float mu  = s * (1.f/512.f);
    float var = (ss - 512.f*mu*mu) * (1.f/511.f);
    float sd  = sqrtf(fmaxf(var, 0.f));
    float inv = 1.f / (sd + 1e-3f);
    float o[8];
    #pragma unroll
    for (int u = 0; u < 8; u++){
        int e = lane*8 + u;
        o[u] = (v[u] - mu) * inv * lnA[e] + lnB[e];
    }
    float* yr = Y + (size_t)row*512 + lane*8;
    *reinterpret_cast<float4*>(yr)     = make_float4(o[0],o[1],o[2],o[3]);
    *reinterpret_cast<float4*>(yr + 4) = make_float4(o[4],o[5],o[6],o[7]);
    if (row < nquery){
        uint4 p;
        p.x = pk2(o[0],o[1]); p.y = pk2(o[2],o[3]);
        p.z = pk2(o[4],o[5]); p.w = pk2(o[6],o[7]);
        *reinterpret_cast<uint4*>(Ybf + (size_t)row*512 + lane*8) = p;
        float* cr = Ycopy + (size_t)row*512 + lane*8;
        *reinterpret_cast<float4*>(cr)     = make_float4(o[0],o[1],o[2],o[3]);
        *reinterpret_cast<float4*>(cr + 4) = make_float4(o[4],o[5],o[6],o[7]);
    }
}

// ---------------------------------------------------------------------------
// Small LSTM cell (D=512, batch=1): 128 blocks x 4 d, one wave per d
// ---------------------------------------------------------------------------
__global__ __launch_bounds__(256) void lstm_small(
    const float* __restrict__ x, const float* __restrict__ hin,
    float* __restrict__ c,
    const float* __restrict__ Wih, const float* __restrict__ Whh,
    const float* __restrict__ bih, const float* __restrict__ bhh,
    float* __restrict__ hout)
{
    __shared__ float xs[512], hs[512];
    __shared__ float gbuf[4][4];
    const int t = threadIdx.x;
    for (int i = t; i < 512; i += 256){ xs[i] = x[i]; hs[i] = hin[i]; }
    __syncthreads();

    const int wd = t >> 6;
    const int lane = t & 63;
    const int g = lane >> 4, p = lane & 15;
    const int d = blockIdx.x*4 + wd;
    const int j = g*512 + d;
    const float4* wi = reinterpret_cast<const float4*>(Wih + (size_t)j*512) + p*8;
    const float4* wh = reinterpret_cast<const float4*>(Whh + (size_t)j*512) + p*8;
    float acc = 0.f;
    #pragma unroll
    for (int q = 0; q < 8; q++){
        float4 wv = wi[q];
        const int kb = p*32 + q*4;
        acc += xs[kb]*wv.x + xs[kb+1]*wv.y + xs[kb+2]*wv.z + xs[kb+3]*wv.w;
        float4 vv = wh[q];
        acc += hs[kb]*vv.x + hs[kb+1]*vv.y + hs[kb+2]*vv.z + hs[kb+3]*vv.w;
    }
    acc += __shfl_xor(acc, 1); acc += __shfl_xor(acc, 2);
    acc += __shfl_xor(acc, 4); acc += __shfl_xor(acc, 8);
    if (p == 0) gbuf[wd][g] = acc + bih[j] + bhh[j];
    __syncthreads();
    if (t < 4){
        int dd = blockIdx.x*4 + t;
        float iv = gbuf[t][0], fv = gbuf[t][1], gv = gbuf[t][2], ov = gbuf[t][3];
        float cn = sigf(fv)*c[dd] + sigf(iv)*ftanh(gv);
        float hn = sigf(ov)*ftanh(cn);
        c[dd] = cn; hout[dd] = hn;
    }
}

// ---------------------------------------------------------------------------
// wvec + finalize merged: all 8 blocks recompute sge into LDS (bit-identical
// expression); block 0 additionally does ae_loss + outp/sgee global writes.
// ---------------------------------------------------------------------------
__global__ __launch_bounds__(256) void wvec_fin_kernel(
    const float* __restrict__ qWhh,
    const float* __restrict__ sg, const float* __restrict__ enc,
    const float* __restrict__ dec,
    float* __restrict__ sgee, float* __restrict__ wvec,
    float* __restrict__ outp)
{
    __shared__ float ss[512];
    __shared__ float red[4];
    const int t = threadIdx.x;
    #pragma unroll
    for (int u = 0; u < 2; u++){
        int d = u*256 + t;
        float v = sg[d] + enc[d] + sg[512+d] + enc[512+d] + sg[1024+d] + enc[1024+d];
        ss[d] = v;
        if (blockIdx.x == 0){ sgee[d] = v; outp[2049 + d] = v; }
    }
    if (blockIdx.x == 0){
        float s = 0.f;
        for (int i = t; i < 1536; i += 256){ float dd = sg[i] - dec[i]; s += dd*dd; }
        s += __shfl_xor(s,1); s += __shfl_xor(s,2); s += __shfl_xor(s,4);
        s += __shfl_xor(s,8); s += __shfl_xor(s,16); s += __shfl_xor(s,32);
        if ((t & 63) == 0) red[t>>6] = s;
        __syncthreads();
        if (t == 0){
            float tot = (red[0]+red[1]+red[2]+red[3]) * (1.f/1536.f);
            outp[2048] = tot;
        }
    }
    __syncthreads();

    const int n = blockIdx.x * 256 + t;
    const int row = (n & 3) * 1024 + (n >> 2);
    const float4* wq = reinterpret_cast<const float4*>(qWhh + (size_t)row*1024 + 512);
    float acc = 0.f;
    for (int kc = 0; kc < 128; kc++){
        float4 wv = wq[kc];
        const int kb = kc*4;
        acc += ss[kb]*wv.x + ss[kb+1]*wv.y + ss[kb+2]*wv.z + ss[kb+3]*wv.w;
    }
    wvec[n] = acc;
}

// ---------------------------------------------------------------------------
// Gate math on packed G: g4 = (i,f,g,o) at G[b*2048 + 4d]
// first!=0: treat c as 0 (base step) — removes the cb memset + zero-read.
// ---------------------------------------------------------------------------
__global__ __launch_bounds__(256) void gate_kernel(
    const float* __restrict__ G, const float* __restrict__ qg,
    float* __restrict__ c, u16* __restrict__ h_bf, int first)
{
    const int idx = blockIdx.x * 256 + threadIdx.x;
    const int b = idx >> 9, d = idx & 511;
    float4 g4 = *reinterpret_cast<const float4*>(G + (size_t)b*2048 + d*4);
    float c0 = first ? 0.f : c[idx];
    float cn = sigf(g4.y)*c0 + sigf(g4.x)*ftanh(g4.z);
    float hn = qg[idx] + sigf(g4.w)*ftanh(cn);
    c[idx] = cn; h_bf[idx] = f2b(hn);
}

// ---------------------------------------------------------------------------
// matching_scores[b] = dot(h[b], sge_enc)
// ---------------------------------------------------------------------------
__global__ __launch_bounds__(256) void scores_kernel(
    const u16* __restrict__ h, const float* __restrict__ sge,
    float* __restrict__ out)
{
    const int wave = threadIdx.x >> 6, lane = threadIdx.x & 63;
    const int row = blockIdx.x * 4 + wave;
    const u16* hr = h + (size_t)row * 512;
    float s = 0.f;
    for (int i = lane; i < 512; i += 64) s += b2f(hr[i]) * sge[i];
    s += __shfl_xor(s,1); s += __shfl_xor(s,2); s += __shfl_xor(s,4);
    s += __shfl_xor(s,8); s += __shfl_xor(s,16); s += __shfl_xor(s,32);
    if (lane == 0) out[row] = s;
}

// ---------------------------------------------------------------------------
extern "C" void kernel_launch(void* const* d_in, const int* in_sizes, int n_in,
                              void* d_out, int out_size, void* d_ws, size_t ws_size,
                              hipStream_t stream)
{
    (void)in_sizes; (void)n_in; (void)out_size; (void)ws_size;

    const int* qlc = (const int*)d_in[2];
    const int* qrc = (const int*)d_in[4];
    const int* slc = (const int*)d_in[6];
    const int* src = (const int*)d_in[8];
    const float* emb = (const float*)d_in[10];
    const float* naW = (const float*)d_in[11];
    const float* naB = (const float*)d_in[12];
    const float* nuW = (const float*)d_in[13];
    const float* nuB = (const float*)d_in[14];
    const float* p1W = (const float*)d_in[15], *p1b = (const float*)d_in[16];
    const float* p2W = (const float*)d_in[17], *p2b = (const float*)d_in[18];
    const float* lnA = (const float*)d_in[19], *lnB = (const float*)d_in[20];
    const float* eWih = (const float*)d_in[21], *eWhh = (const float*)d_in[22];
    const float* eBih = (const float*)d_in[23], *eBhh = (const float*)d_in[24];
    const float* dWih = (const float*)d_in[25], *dWhh = (const float*)d_in[26];
    const float* dBih = (const float*)d_in[27], *dBhh = (const float*)d_in[28];
    const float* qWih = (const float*)d_in[33], *qWhh = (const float*)d_in[34];
    const float* qBih = (const float*)d_in[35], *qBhh = (const float*)d_in[36];
    float* out = (float*)d_out;

    float* w = (float*)d_ws;
    size_t off = 0;
    auto alloc = [&](size_t nelem){ float* p = w + off; off += nelem; return p; };
    float* qn    = alloc(2176ull*512);   // neighbor f32 (2051 rows used)
    float* qg    = alloc(2176ull*512);   // query_g f32 (+ sg rows 2048..2050)
    float* enc   = alloc(1536);
    float* dec   = alloc(1536);
    float* zc    = alloc(1024);
    float* sgee  = alloc(512);
    float* wv    = alloc(2048);
    float* bc    = alloc(2048);
    float* nawfF = alloc(65536);         // 131072 u16 frag-packed naW
    float* base  = alloc(2048ull*2048);  // + Zq, qn_bf aliases
    float* G     = alloc(2048ull*2048);  // + Hq_bf, qg_bf aliases
    float* cb    = alloc(2048ull*512);
    float* hbfF  = alloc(524288);        // h bf16
    float* p1WbF = alloc(262144);
    float* p2WbF = alloc(262144);
    float* WihSF = alloc(524288);
    float* WhhSF = alloc(524288);

    u16* nawf   = (u16*)nawfF;
    u16* p1Wb   = (u16*)p1WbF;
    u16* p2Wb   = (u16*)p2WbF;
    u16* WihSel = (u16*)WihSF;
    u16* WhhSel = (u16*)WhhSF;
    u16* h_bf   = (u16*)hbfF;
    float* Zq   = base;                       // 2176x512 f32
    u16* qn_bf  = (u16*)(base + 2097152);     // 2176x512 u16
    u16* Hq_bf  = (u16*)G;                    // 2176x1024 u16
    u16* qg_bf  = (u16*)(G + 2097152);        // 2176x512 u16 (2048 used)
    float* sg   = qg + 2048ull*512;
    float* zbuf = zc;
    float* cst  = zc + 512;

    // weight preprocessing + zc zero (memset folded in)
    prep_kernel<<<2124, 256, 0, stream>>>(p1W, p2W, naW, qWih, qWhh, qBih, qBhh,
                                          p1Wb, p2Wb, nawf, WihSel, WhhSel, bc, zc);

    // neighbor encoder: (row, side) blocks — 2051 rows x 2 sides
    neighbor_v6<<<4102, 256, 0, stream>>>(qlc, qrc, slc, src, emb,
                                          nawf, naB, nuW, nuB, qn, qn_bf);

    // support encoder fused over 2051 rows: H=relu(X@p1W^T+b); Z=H@p2W^T+b; LN
    gemm_tn<<<dim3(16,17), 256, 0, stream>>>(qn_bf, 512, p1Wb, 512, p1b, nullptr, 0,
                                             nullptr, Hq_bf, 1024, 512, 1);
    gemm_tn<<<dim3(8,17), 256, 0, stream>>>(Hq_bf, 1024, p2Wb, 1024, p2b, nullptr, 0,
                                            Zq, nullptr, 512, 1024, 0);
    ln_kernel<<<513, 256, 0, stream>>>(Zq, qn, 2051, 2048, lnA, lnB, qg, qg_bf, out + 2561);

    // set autoencoder
    lstm_small<<<128, 256, 0, stream>>>(sg,        zbuf,      cst, eWih, eWhh, eBih, eBhh, enc);
    lstm_small<<<128, 256, 0, stream>>>(sg + 512,  enc,       cst, eWih, eWhh, eBih, eBhh, enc + 512);
    lstm_small<<<128, 256, 0, stream>>>(sg + 1024, enc + 512, cst, eWih, eWhh, eBih, eBhh, enc + 1024);
    lstm_small<<<128, 256, 0, stream>>>(enc + 1024, enc + 1024, cst, dWih, dWhh, dBih, dBhh, dec);
    lstm_small<<<128, 256, 0, stream>>>(dec,        dec,        cst, dWih, dWhh, dBih, dBhh, dec + 512);
    lstm_small<<<128, 256, 0, stream>>>(dec + 512,  dec + 512,  cst, dWih, dWhh, dBih, dBhh, dec + 1024);

    // ae_loss + sge + wvec (merged)
    wvec_fin_kernel<<<8, 256, 0, stream>>>(qWhh, sg, enc, dec, sgee, wv, out);

    // query encoder: base = qg@WihSel^T + bc; 4 steps (live half only)
    gemm_tn<<<dim3(32,16), 256, 0, stream>>>(qg_bf, 512, WihSel, 512, bc, nullptr, 0,
                                             base, nullptr, 2048, 512, 0);
    gate_kernel<<<4096, 256, 0, stream>>>(base, qg, cb, h_bf, 1);
    for (int s = 0; s < 3; s++){
        gemm_tn<<<dim3(32,16), 256, 0, stream>>>(h_bf, 512, WhhSel, 512, wv, base, 2048,
                                                 G, nullptr, 2048, 512, 0);
        gate_kernel<<<4096, 256, 0, stream>>>(G, qg, cb, h_bf, 0);
    }

    scores_kernel<<<512, 256, 0, stream>>>(h_bf, sgee, out);
}

// Round 10
// 631.938 us; speedup vs baseline: 1.0394x; 1.0000x over previous
//
#include <hip/hip_runtime.h>
#include <hip/hip_bf16.h>

typedef unsigned short u16;
typedef __attribute__((ext_vector_type(8))) short bf16x8;
typedef __attribute__((ext_vector_type(4))) float f32x4;
#define MFMA16(a,b,c) __builtin_amdgcn_mfma_f32_16x16x32_bf16(a,b,c,0,0,0)
#define VPAD 100000

__device__ __forceinline__ float sigf(float x){ return 1.0f/(1.0f + __expf(-x)); }
__device__ __forceinline__ float ftanh(float x){
    float ax = fabsf(x);
    float e = __expf(-2.f*ax);
    float r = (1.f - e) / (1.f + e);
    return copysignf(r, x);
}
__device__ __forceinline__ u16 f2b(float f){
    unsigned u = __float_as_uint(f);
    u += 0x7fffu + ((u >> 16) & 1u);
    return (u16)(u >> 16);
}
__device__ __forceinline__ unsigned int pk2(float x, float y){
    return ((unsigned)f2b(y) << 16) | (unsigned)f2b(x);
}
__device__ __forceinline__ float b2f(u16 u){
    return __uint_as_float(((unsigned int)u) << 16);
}
__device__ __forceinline__ uint4 pk8(float4 x, float4 y){
    uint4 o;
    o.x = pk2(x.x,x.y); o.y = pk2(x.z,x.w);
    o.z = pk2(y.x,y.y); o.w = pk2(y.z,y.w);
    return o;
}

// ---------------------------------------------------------------------------
// prep: weight preprocessing + zc zero-init (memset folded in).
//  p1W/p2W f32->bf16; qWih/qWhh live-row pack (n'=4d+gate); naW frag blob;
//  bias combine; zc[0..1023] = 0.
// ---------------------------------------------------------------------------
__global__ __launch_bounds__(256) void prep_kernel(
    const float* __restrict__ p1W, const float* __restrict__ p2W,
    const float* __restrict__ naW,
    const float* __restrict__ qWih, const float* __restrict__ qWhh,
    const float* __restrict__ qBih, const float* __restrict__ qBhh,
    u16* __restrict__ p1Wb, u16* __restrict__ p2Wb,
    u16* __restrict__ nawf, u16* __restrict__ WihS, u16* __restrict__ WhhS,
    float* __restrict__ bc, float* __restrict__ zc)
{
    const long gid = (long)blockIdx.x * 256 + threadIdx.x;
    const long E0 = 131072;         // p1W float4 units
    const long E1 = E0 + 131072;    // p2W
    const long E2 = E1 + 131072;    // Wih pack (8 u16/thread)
    const long E3 = E2 + 131072;    // Whh pack
    const long E4 = E3 + 16384;     // naW frag pack
    const long E5 = E4 + 2048;      // bias comb
    const long E6 = E5 + 1024;      // zc zero
    if (gid < E0){
        float4 v = reinterpret_cast<const float4*>(p1W)[gid];
        uint2 s; s.x = pk2(v.x,v.y); s.y = pk2(v.z,v.w);
        reinterpret_cast<uint2*>(p1Wb)[gid] = s;
    } else if (gid < E1){
        long i = gid - E0;
        float4 v = reinterpret_cast<const float4*>(p2W)[i];
        uint2 s; s.x = pk2(v.x,v.y); s.y = pk2(v.z,v.w);
        reinterpret_cast<uint2*>(p2Wb)[i] = s;
    } else if (gid < E2){
        long j = gid - E1;
        int n = (int)(j >> 6), c8 = (int)(j & 63);
        int srow = (n & 3) * 1024 + (n >> 2);
        const float* sp = qWih + (size_t)srow * 512 + c8 * 8;
        float4 a = *reinterpret_cast<const float4*>(sp);
        float4 b = *reinterpret_cast<const float4*>(sp + 4);
        *reinterpret_cast<uint4*>(WihS + (size_t)n*512 + c8*8) = pk8(a,b);
    } else if (gid < E3){
        long j = gid - E2;
        int n = (int)(j >> 6), c8 = (int)(j & 63);
        int srow = (n & 3) * 1024 + (n >> 2);
        const float* sp = qWhh + (size_t)srow * 1024 + c8 * 8;
        float4 a = *reinterpret_cast<const float4*>(sp);
        float4 b = *reinterpret_cast<const float4*>(sp + 4);
        *reinterpret_cast<uint4*>(WhhS + (size_t)n*512 + c8*8) = pk8(a,b);
    } else if (gid < E4){
        long j = gid - E3;                 // 0..16383
        int f = (int)(j >> 6), lane = (int)(j & 63);
        int ks = f >> 4, ig = f & 15;
        int col = lane & 15, quad = lane >> 4;
        int n = ig*16 + col;
        int k0 = ks*32 + quad*8;
        const float* sp = naW + (size_t)n*512 + k0;
        float4 a = *reinterpret_cast<const float4*>(sp);
        float4 b = *reinterpret_cast<const float4*>(sp + 4);
        *reinterpret_cast<uint4*>(nawf + j*8) = pk8(a,b);
    } else if (gid < E5){
        int n = (int)(gid - E4);
        int row = (n & 3) * 1024 + (n >> 2);
        bc[n] = qBih[row] + qBhh[row];
    } else if (gid < E6){
        zc[gid - E5] = 0.f;
    }
}

// ---------------------------------------------------------------------------
// Neighbor encoder v6 (CHAMPION, 117us): one block per (row, side), grid 4102.
// Side-split + ent f32 LDS stash: phase p=1 also copies the gathered f32 ent
// rows into LDS; agg reads LDS instead of re-gathering from global.
// Ledger: v4=138 v5=139 v6=117 v7=145. LDS 49.7KB -> 3 blocks/CU; occupancy
// 21% hurts (v7), 31-74% is time-neutral (v5/v6). FETCH ~123MB = compulsory.
// ---------------------------------------------------------------------------
__global__ __launch_bounds__(256, 3) void neighbor_v6(
    const int* __restrict__ qL, const int* __restrict__ qR,
    const int* __restrict__ sL, const int* __restrict__ sR,
    const float* __restrict__ emb,
    const u16* __restrict__ nawf,
    const float* __restrict__ naB, const float* __restrict__ nuW,
    const float* __restrict__ nuB,
    float* __restrict__ out, u16* __restrict__ out_bf)
{
    __shared__ __align__(16) u16 frg[16*512];     // 16 frags x 1KB
    __shared__ __align__(16) float entf[32*256];  // f32 ent stash (32KB)
    __shared__ int relid[32];
    __shared__ int entid[32];
    __shared__ float logit[32];
    __shared__ float att[32];

    const int t = threadIdx.x;
    const int bx = blockIdx.x;     // 0..4101
    const int row = bx >> 1;       // 0..2050
    const int s = bx & 1;          // side: 0=L 1=R
    if (t < 64){
        int k = t >> 1, which = t & 1;
        const int* conn;
        if (row < 2048) conn = (s ? qR : qL) + (size_t)row * 60;
        else            conn = (s ? sR : sL) + (size_t)(row - 2048) * 60;
        int id = (k < 30) ? conn[k*2 + which] : VPAD;
        if (which) entid[k] = id; else relid[k] = id;
    }
    if (t >= 64 && t < 96) logit[t-64] = 0.f;
    __syncthreads();

    const int w = t >> 6, lane = t & 63;
    const int col = lane & 15, quad = lane >> 4;

    // decode gather unit (constant per thread across phases): 1024 units
    int gc[4], gk[4];
    #pragma unroll
    for (int i = 0; i < 4; i++){
        int idx = i*256 + t;
        gc[i] = idx & 31;            // 8-elem chunk within 256-elem half
        gk[i] = (idx >> 5) & 31;     // row 0..31
    }

    f32x4 acc[2][4] = {};

    #pragma unroll
    for (int p = 0; p < 2; p++){
        // gather phase p (p=0: rel, p=1: ent)
        #pragma unroll
        for (int i = 0; i < 4; i++){
            int k = gk[i], c = gc[i];
            int e0 = c*8;
            int id = p ? entid[k] : relid[k];
            const float* ptr = emb + (size_t)id*256 + e0;
            float4 x = *reinterpret_cast<const float4*>(ptr);
            float4 y = *reinterpret_cast<const float4*>(ptr + 4);
            int ksl = e0 >> 5, q = (e0 >> 3) & 3;
            int mt = k >> 4, cl = k & 15;
            int ln = q*16 + cl;
            u16* dst = frg + (((mt*8 + ksl)*64) + ln)*8;
            *reinterpret_cast<uint4*>(dst) = pk8(x, y);
            if (p){
                float* fd = entf + k*256 + e0;
                *reinterpret_cast<float4*>(fd)     = x;
                *reinterpret_cast<float4*>(fd + 4) = y;
            }
        }
        __syncthreads();

        // MFMA phase: 8 local ks steps
        #pragma unroll
        for (int ksl = 0; ksl < 8; ksl++){
            bf16x8 a[2], b[4];
            #pragma unroll
            for (int u = 0; u < 2; u++)
                a[u] = *reinterpret_cast<const bf16x8*>(frg + (((u*8 + ksl)*64) + lane)*8);
            const int ks = p*8 + ksl;
            #pragma unroll
            for (int i = 0; i < 4; i++)
                b[i] = *reinterpret_cast<const bf16x8*>(nawf + ((size_t)(ks*16 + w*4 + i)*64 + lane)*8);
            #pragma unroll
            for (int i = 0; i < 4; i++)
                #pragma unroll
                for (int u = 0; u < 2; u++)
                    acc[u][i] = MFMA16(a[u], b[i], acc[u][i]);
        }
        __syncthreads();
    }

    // logits
    float nu[4], nbv[4];
    #pragma unroll
    for (int i = 0; i < 4; i++){
        int n = (w*4 + i)*16 + col;
        nu[i] = nuW[n]; nbv[i] = naB[n];
    }
    #pragma unroll
    for (int u = 0; u < 2; u++){
        #pragma unroll
        for (int r = 0; r < 4; r++){
            int m = u*16 + quad*4 + r;
            float v = 0.f;
            #pragma unroll
            for (int i = 0; i < 4; i++)
                v += ftanh(acc[u][i][r] + nbv[i]) * nu[i];
            v += __shfl_xor(v, 1); v += __shfl_xor(v, 2);
            v += __shfl_xor(v, 4); v += __shfl_xor(v, 8);
            if (col == 0 && m < 30) atomicAdd(&logit[m], v);
        }
    }
    __syncthreads();

    if (t == 0){
        const float nub = nuB[0];
        float mx = -1e30f;
        float lg[30];
        #pragma unroll
        for (int k = 0; k < 30; k++){
            float L = logit[k] + nub;
            lg[k] = L; mx = fmaxf(mx, L);
        }
        float sm = 0.f;
        #pragma unroll
        for (int k = 0; k < 30; k++){ float e = __expf(lg[k]-mx); att[k] = e; sm += e; }
        float inv = 1.f / sm;
        #pragma unroll
        for (int k = 0; k < 30; k++) att[k] *= inv;
    }
    __syncthreads();

    // agg: thread t = column e (0..255); ent rows from LDS stash (bit-exact)
    const int e = t;
    float agg = 0.f;
    #pragma unroll
    for (int k = 0; k < 30; k++)
        agg += att[k] * entf[k*256 + e];
    float r = ftanh(agg);
    size_t oi = (size_t)row*512 + s*256 + e;
    out[oi] = r;
    out_bf[oi] = f2b(r);
}

// ---------------------------------------------------------------------------
// gemm_tn: C[m,n] = act( A[m,:]·B[n,:] + bias[n] (+addD[m,n]) )
// A bf16 [M x lda], B bf16 [N x ldb]. 128x64 tile, 4 waves of 64x32.
// T14 register double-buffer: loads for kc+1 issued right after the LDS
// write of kc, so L2 latency (~200cy) hides under MFMA(kc)+barrier instead
// of being exposed at the next LDS write. Same LDS contents + MFMA order
// per iteration -> bit-exact vs the single-buffered version.
// ---------------------------------------------------------------------------
__global__ __launch_bounds__(256) void gemm_tn(
    const u16* __restrict__ A, int lda,
    const u16* __restrict__ B, int ldb,
    const float* __restrict__ bias,
    const float* __restrict__ addD, int ldd,
    float* __restrict__ Cf, u16* __restrict__ Cbf, int ldc,
    int K, int relu)
{
    __shared__ __align__(16) u16 As[128][72];
    __shared__ __align__(16) u16 Bs[64][72];
    const int t = threadIdx.x;
    const int m0 = blockIdx.y * 128, n0 = blockIdx.x * 64;
    const int w = t >> 6, lane = t & 63;
    const int col = lane & 15, quad = lane >> 4;
    const int wm = (w & 1) * 64, wn = (w >> 1) * 32;

    int arow[4], aseg[4], brow[2], bseg[2];
    #pragma unroll
    for (int i = 0; i < 4; i++){
        int idx = i*256 + t; arow[i] = idx >> 3; aseg[i] = (idx & 7) * 8;
    }
    #pragma unroll
    for (int i = 0; i < 2; i++){
        int idx = i*256 + t; brow[i] = idx >> 3; bseg[i] = (idx & 7) * 8;
    }

    f32x4 acc[4][2] = {};

    const int KC = K >> 6;
    uint4 av[4], bv[2];
    #pragma unroll
    for (int i = 0; i < 4; i++)
        av[i] = *reinterpret_cast<const uint4*>(A + (size_t)(m0 + arow[i])*lda + aseg[i]);
    #pragma unroll
    for (int i = 0; i < 2; i++)
        bv[i] = *reinterpret_cast<const uint4*>(B + (size_t)(n0 + brow[i])*ldb + bseg[i]);

    for (int kc = 0; kc < KC; kc++){
        __syncthreads();   // prior MFMA done reading LDS
        #pragma unroll
        for (int i = 0; i < 4; i++)
            *reinterpret_cast<uint4*>(&As[arow[i]][aseg[i]]) = av[i];
        #pragma unroll
        for (int i = 0; i < 2; i++)
            *reinterpret_cast<uint4*>(&Bs[brow[i]][bseg[i]]) = bv[i];
        if (kc + 1 < KC){
            #pragma unroll
            for (int i = 0; i < 4; i++)
                av[i] = *reinterpret_cast<const uint4*>(A + (size_t)(m0 + arow[i])*lda + (kc+1)*64 + aseg[i]);
            #pragma unroll
            for (int i = 0; i < 2; i++)
                bv[i] = *reinterpret_cast<const uint4*>(B + (size_t)(n0 + brow[i])*ldb + (kc+1)*64 + bseg[i]);
        }
        __syncthreads();   // LDS tile kc visible to all
        #pragma unroll
        for (int ks = 0; ks < 2; ks++){
            const int k0 = ks*32 + quad*8;
            bf16x8 af[4], bf[2];
            #pragma unroll
            for (int i = 0; i < 4; i++) af[i] = *reinterpret_cast<const bf16x8*>(&As[wm + i*16 + col][k0]);
            #pragma unroll
            for (int j = 0; j < 2; j++) bf[j] = *reinterpret_cast<const bf16x8*>(&Bs[wn + j*16 + col][k0]);
            #pragma unroll
            for (int i = 0; i < 4; i++)
                #pragma unroll
                for (int j = 0; j < 2; j++)
                    acc[i][j] = MFMA16(af[i], bf[j], acc[i][j]);
        }
    }

    #pragma unroll
    for (int j = 0; j < 2; j++){
        int n = n0 + wn + j*16 + col;
        float bj = bias[n];
        #pragma unroll
        for (int i = 0; i < 4; i++){
            #pragma unroll
            for (int r = 0; r < 4; r++){
                int m = m0 + wm + i*16 + quad*4 + r;
                float v = acc[i][j][r] + bj;
                if (addD) v += addD[(size_t)m*ldd + n];
                if (relu) v = fmaxf(v, 0.f);
                if (Cf)  Cf[(size_t)m*ldc + n] = v;
                if (Cbf) Cbf[(size_t)m*ldc + n] = f2b(v);
            }
        }
    }
}

// ---------------------------------------------------------------------------
// LayerNorm(Z + X), ddof=1, eps on sigma. One wave per row; 2051 rows.
// ---------------------------------------------------------------------------
__global__ __launch_bounds__(256) void ln_kernel(
    const float* __restrict__ Z, const float* __restrict__ X, int N, int nquery,
    const float* __restrict__ lnA, const float* __restrict__ lnB,
    float* __restrict__ Y, u16* __restrict__ Ybf, float* __restrict__ Ycopy)
{
    const int wv = threadIdx.x >> 6, lane = threadIdx.x & 63;
    const int row = blockIdx.x * 4 + wv;
    if (row >= N) return;
    const float* z = Z + (size_t)row * 512;
    const float* x = X + (size_t)row * 512;
    float v[8];
    float s = 0.f, ss = 0.f;
    {
        float4 z0 = *reinterpret_cast<const float4*>(z + lane*8);
        float4 z1 = *reinterpret_cast<const float4*>(z + lane*8 + 4);
        float4 x0 = *reinterpret_cast<const float4*>(x + lane*8);
        float4 x1 = *reinterpret_cast<const float4*>(x + lane*8 + 4);
        v[0]=z0.x+x0.x; v[1]=z0.y+x0.y; v[2]=z0.z+x0.z; v[3]=z0.w+x0.w;
        v[4]=z1.x+x1.x; v[5]=z1.y+x1.y; v[6]=z1.z+x1.z; v[7]=z1.w+x1.w;
    }
    #pragma unroll
    for (int u = 0; u < 8; u++){ s += v[u]; ss += v[u]*v[u]; }
    #pragma unroll
    for (int d = 1; d < 64; d <<= 1){
        s  += __shfl_xor(s, d);
        ss += __shfl_xor(ss, d);
    }
    float mu  = s * (1.f/512.f);
    float var = (ss - 512.f*mu*mu) * (1.f/511.f);
    float sd  = sqrtf(fmaxf(var, 0.f));
    float inv = 1.f / (sd + 1e-3f);
    float o[8];
    #pragma unroll
    for (int u = 0; u < 8; u++){
        int e = lane*8 + u;
        o[u] = (v[u] - mu) * inv * lnA[e] + lnB[e];
    }
    float* yr = Y + (size_t)row*512 + lane*8;
    *reinterpret_cast<float4*>(yr)     = make_float4(o[0],o[1],o[2],o[3]);
    *reinterpret_cast<float4*>(yr + 4) = make_float4(o[4],o[5],o[6],o[7]);
    if (row < nquery){
        uint4 p;
        p.x = pk2(o[0],o[1]); p.y = pk2(o[2],o[3]);
        p.z = pk2(o[4],o[5]); p.w = pk2(o[6],o[7]);
        *reinterpret_cast<uint4*>(Ybf + (size_t)row*512 + lane*8) = p;
        float* cr = Ycopy + (size_t)row*512 + lane*8;
        *reinterpret_cast<float4*>(cr)     = make_float4(o[0],o[1],o[2],o[3]);
        *reinterpret_cast<float4*>(cr + 4) = make_float4(o[4],o[5],o[6],o[7]);
    }
}

// ---------------------------------------------------------------------------
// Small LSTM cell (D=512, batch=1): 128 blocks x 4 d, one wave per d
// ---------------------------------------------------------------------------
__global__ __launch_bounds__(256) void lstm_small(
    const float* __restrict__ x, const float* __restrict__ hin,
    float* __restrict__ c,
    const float* __restrict__ Wih, const float* __restrict__ Whh,
    const float* __restrict__ bih, const float* __restrict__ bhh,
    float* __restrict__ hout)
{
    __shared__ float xs[512], hs[512];
    __shared__ float gbuf[4][4];
    const int t = threadIdx.x;
    for (int i = t; i < 512; i += 256){ xs[i] = x[i]; hs[i] = hin[i]; }
    __syncthreads();

    const int wd = t >> 6;
    const int lane = t & 63;
    const int g = lane >> 4, p = lane & 15;
    const int d = blockIdx.x*4 + wd;
    const int j = g*512 + d;
    const float4* wi = reinterpret_cast<const float4*>(Wih + (size_t)j*512) + p*8;
    const float4* wh = reinterpret_cast<const float4*>(Whh + (size_t)j*512) + p*8;
    float acc = 0.f;
    #pragma unroll
    for (int q = 0; q < 8; q++){
        float4 wv = wi[q];
        const int kb = p*32 + q*4;
        acc += xs[kb]*wv.x + xs[kb+1]*wv.y + xs[kb+2]*wv.z + xs[kb+3]*wv.w;
        float4 vv = wh[q];
        acc += hs[kb]*vv.x + hs[kb+1]*vv.y + hs[kb+2]*vv.z + hs[kb+3]*vv.w;
    }
    acc += __shfl_xor(acc, 1); acc += __shfl_xor(acc, 2);
    acc += __shfl_xor(acc, 4); acc += __shfl_xor(acc, 8);
    if (p == 0) gbuf[wd][g] = acc + bih[j] + bhh[j];
    __syncthreads();
    if (t < 4){
        int dd = blockIdx.x*4 + t;
        float iv = gbuf[t][0], fv = gbuf[t][1], gv = gbuf[t][2], ov = gbuf[t][3];
        float cn = sigf(fv)*c[dd] + sigf(iv)*ftanh(gv);
        float hn = sigf(ov)*ftanh(cn);
        c[dd] = cn; hout[dd] = hn;
    }
}

// ---------------------------------------------------------------------------
// wvec + finalize merged: all 8 blocks recompute sge into LDS (bit-identical
// expression); block 0 additionally does ae_loss + outp/sgee global writes.
// ---------------------------------------------------------------------------
__global__ __launch_bounds__(256) void wvec_fin_kernel(
    const float* __restrict__ qWhh,
    const float* __restrict__ sg, const float* __restrict__ enc,
    const float* __restrict__ dec,
    float* __restrict__ sgee, float* __restrict__ wvec,
    float* __restrict__ outp)
{
    __shared__ float ss[512];
    __shared__ float red[4];
    const int t = threadIdx.x;
    #pragma unroll
    for (int u = 0; u < 2; u++){
        int d = u*256 + t;
        float v = sg[d] + enc[d] + sg[512+d] + enc[512+d] + sg[1024+d] + enc[1024+d];
        ss[d] = v;
        if (blockIdx.x == 0){ sgee[d] = v; outp[2049 + d] = v; }
    }
    if (blockIdx.x == 0){
        float s = 0.f;
        for (int i = t; i < 1536; i += 256){ float dd = sg[i] - dec[i]; s += dd*dd; }
        s += __shfl_xor(s,1); s += __shfl_xor(s,2); s += __shfl_xor(s,4);
        s += __shfl_xor(s,8); s += __shfl_xor(s,16); s += __shfl_xor(s,32);
        if ((t & 63) == 0) red[t>>6] = s;
        __syncthreads();
        if (t == 0){
            float tot = (red[0]+red[1]+red[2]+red[3]) * (1.f/1536.f);
            outp[2048] = tot;
        }
    }
    __syncthreads();

    const int n = blockIdx.x * 256 + t;
    const int row = (n & 3) * 1024 + (n >> 2);
    const float4* wq = reinterpret_cast<const float4*>(qWhh + (size_t)row*1024 + 512);
    float acc = 0.f;
    for (int kc = 0; kc < 128; kc++){
        float4 wv = wq[kc];
        const int kb = kc*4;
        acc += ss[kb]*wv.x + ss[kb+1]*wv.y + ss[kb+2]*wv.z + ss[kb+3]*wv.w;
    }
    wvec[n] = acc;
}

// ---------------------------------------------------------------------------
// Gate math on packed G: g4 = (i,f,g,o) at G[b*2048 + 4d]
// first!=0: treat c as 0 (base step) — removes the cb memset + zero-read.
// ---------------------------------------------------------------------------
__global__ __launch_bounds__(256) void gate_kernel(
    const float* __restrict__ G, const float* __restrict__ qg,
    float* __restrict__ c, u16* __restrict__ h_bf, int first)
{
    const int idx = blockIdx.x * 256 + threadIdx.x;
    const int b = idx >> 9, d = idx & 511;
    float4 g4 = *reinterpret_cast<const float4*>(G + (size_t)b*2048 + d*4);
    float c0 = first ? 0.f : c[idx];
    float cn = sigf(g4.y)*c0 + sigf(g4.x)*ftanh(g4.z);
    float hn = qg[idx] + sigf(g4.w)*ftanh(cn);
    c[idx] = cn; h_bf[idx] = f2b(hn);
}

// ---------------------------------------------------------------------------
// matching_scores[b] = dot(h[b], sge_enc)
// ---------------------------------------------------------------------------
__global__ __launch_bounds__(256) void scores_kernel(
    const u16* __restrict__ h, const float* __restrict__ sge,
    float* __restrict__ out)
{
    const int wave = threadIdx.x >> 6, lane = threadIdx.x & 63;
    const int row = blockIdx.x * 4 + wave;
    const u16* hr = h + (size_t)row * 512;
    float s = 0.f;
    for (int i = lane; i < 512; i += 64) s += b2f(hr[i]) * sge[i];
    s += __shfl_xor(s,1); s += __shfl_xor(s,2); s += __shfl_xor(s,4);
    s += __shfl_xor(s,8); s += __shfl_xor(s,16); s += __shfl_xor(s,32);
    if (lane == 0) out[row] = s;
}

// ---------------------------------------------------------------------------
extern "C" void kernel_launch(void* const* d_in, const int* in_sizes, int n_in,
                              void* d_out, int out_size, void* d_ws, size_t ws_size,
                              hipStream_t stream)
{
    (void)in_sizes; (void)n_in; (void)out_size; (void)ws_size;

    const int* qlc = (const int*)d_in[2];
    const int* qrc = (const int*)d_in[4];
    const int* slc = (const int*)d_in[6];
    const int* src = (const int*)d_in[8];
    const float* emb = (const float*)d_in[10];
    const float* naW = (const float*)d_in[11];
    const float* naB = (const float*)d_in[12];
    const float* nuW = (const float*)d_in[13];
    const float* nuB = (const float*)d_in[14];
    const float* p1W = (const float*)d_in[15], *p1b = (const float*)d_in[16];
    const float* p2W = (const float*)d_in[17], *p2b = (const float*)d_in[18];
    const float* lnA = (const float*)d_in[19], *lnB = (const float*)d_in[20];
    const float* eWih = (const float*)d_in[21], *eWhh = (const float*)d_in[22];
    const float* eBih = (const float*)d_in[23], *eBhh = (const float*)d_in[24];
    const float* dWih = (const float*)d_in[25], *dWhh = (const float*)d_in[26];
    const float* dBih = (const float*)d_in[27], *dBhh = (const float*)d_in[28];
    const float* qWih = (const float*)d_in[33], *qWhh = (const float*)d_in[34];
    const float* qBih = (const float*)d_in[35], *qBhh = (const float*)d_in[36];
    float* out = (float*)d_out;

    float* w = (float*)d_ws;
    size_t off = 0;
    auto alloc = [&](size_t nelem){ float* p = w + off; off += nelem; return p; };
    float* qn    = alloc(2176ull*512);   // neighbor f32 (2051 rows used)
    float* qg    = alloc(2176ull*512);   // query_g f32 (+ sg rows 2048..2050)
    float* enc   = alloc(1536);
    float* dec   = alloc(1536);
    float* zc    = alloc(1024);
    float* sgee  = alloc(512);
    float* wv    = alloc(2048);
    float* bc    = alloc(2048);
    float* nawfF = alloc(65536);         // 131072 u16 frag-packed naW
    float* base  = alloc(2048ull*2048);  // + Zq, qn_bf aliases
    float* G     = alloc(2048ull*2048);  // + Hq_bf, qg_bf aliases
    float* cb    = alloc(2048ull*512);
    float* hbfF  = alloc(524288);        // h bf16
    float* p1WbF = alloc(262144);
    float* p2WbF = alloc(262144);
    float* WihSF = alloc(524288);
    float* WhhSF = alloc(524288);

    u16* nawf   = (u16*)nawfF;
    u16* p1Wb   = (u16*)p1WbF;
    u16* p2Wb   = (u16*)p2WbF;
    u16* WihSel = (u16*)WihSF;
    u16* WhhSel = (u16*)WhhSF;
    u16* h_bf   = (u16*)hbfF;
    float* Zq   = base;                       // 2176x512 f32
    u16* qn_bf  = (u16*)(base + 2097152);     // 2176x512 u16
    u16* Hq_bf  = (u16*)G;                    // 2176x1024 u16
    u16* qg_bf  = (u16*)(G + 2097152);        // 2176x512 u16 (2048 used)
    float* sg   = qg + 2048ull*512;
    float* zbuf = zc;
    float* cst  = zc + 512;

    // weight preprocessing + zc zero (memset folded in)
    prep_kernel<<<2124, 256, 0, stream>>>(p1W, p2W, naW, qWih, qWhh, qBih, qBhh,
                                          p1Wb, p2Wb, nawf, WihSel, WhhSel, bc, zc);

    // neighbor encoder: (row, side) blocks — 2051 rows x 2 sides
    neighbor_v6<<<4102, 256, 0, stream>>>(qlc, qrc, slc, src, emb,
                                          nawf, naB, nuW, nuB, qn, qn_bf);

    // support encoder fused over 2051 rows: H=relu(X@p1W^T+b); Z=H@p2W^T+b; LN
    gemm_tn<<<dim3(16,17), 256, 0, stream>>>(qn_bf, 512, p1Wb, 512, p1b, nullptr, 0,
                                             nullptr, Hq_bf, 1024, 512, 1);
    gemm_tn<<<dim3(8,17), 256, 0, stream>>>(Hq_bf, 1024, p2Wb, 1024, p2b, nullptr, 0,
                                            Zq, nullptr, 512, 1024, 0);
    ln_kernel<<<513, 256, 0, stream>>>(Zq, qn, 2051, 2048, lnA, lnB, qg, qg_bf, out + 2561);

    // set autoencoder
    lstm_small<<<128, 256, 0, stream>>>(sg,        zbuf,      cst, eWih, eWhh, eBih, eBhh, enc);
    lstm_small<<<128, 256, 0, stream>>>(sg + 512,  enc,       cst, eWih, eWhh, eBih, eBhh, enc + 512);
    lstm_small<<<128, 256, 0, stream>>>(sg + 1024, enc + 512, cst, eWih, eWhh, eBih, eBhh, enc + 1024);
    lstm_small<<<128, 256, 0, stream>>>(enc + 1024, enc + 1024, cst, dWih, dWhh, dBih, dBhh, dec);
    lstm_small<<<128, 256, 0, stream>>>(dec,        dec,        cst, dWih, dWhh, dBih, dBhh, dec + 512);
    lstm_small<<<128, 256, 0, stream>>>(dec + 512,  dec + 512,  cst, dWih, dWhh, dBih, dBhh, dec + 1024);

    // ae_loss + sge + wvec (merged)
    wvec_fin_kernel<<<8, 256, 0, stream>>>(qWhh, sg, enc, dec, sgee, wv, out);

    // query encoder: base = qg@WihSel^T + bc; 4 steps (live half only)
    gemm_tn<<<dim3(32,16), 256, 0, stream>>>(qg_bf, 512, WihSel, 512, bc, nullptr, 0,
                                             base, nullptr, 2048, 512, 0);
    gate_kernel<<<4096, 256, 0, stream>>>(base, qg, cb, h_bf, 1);
    for (int s = 0; s < 3; s++){
        gemm_tn<<<dim3(32,16), 256, 0, stream>>>(h_bf, 512, WhhSel, 512, wv, base, 2048,
                                                 G, nullptr, 2048, 512, 0);
        gate_kernel<<<4096, 256, 0, stream>>>(G, qg, cb, h_bf, 0);
    }

    scores_kernel<<<512, 256, 0, stream>>>(h_bf, sgee, out);
}

// Round 11
// 630.149 us; speedup vs baseline: 1.0424x; 1.0028x over previous
//
#include <hip/hip_runtime.h>
#include <hip/hip_bf16.h>

typedef unsigned short u16;
typedef __attribute__((ext_vector_type(8))) short bf16x8;
typedef __attribute__((ext_vector_type(4))) float f32x4;
#define MFMA16(a,b,c) __builtin_amdgcn_mfma_f32_16x16x32_bf16(a,b,c,0,0,0)
#define VPAD 100000

__device__ __forceinline__ float sigf(float x){ return 1.0f/(1.0f + __expf(-x)); }
__device__ __forceinline__ float ftanh(float x){
    float ax = fabsf(x);
    float e = __expf(-2.f*ax);
    float r = (1.f - e) / (1.f + e);
    return copysignf(r, x);
}
__device__ __forceinline__ u16 f2b(float f){
    unsigned u = __float_as_uint(f);
    u += 0x7fffu + ((u >> 16) & 1u);
    return (u16)(u >> 16);
}
__device__ __forceinline__ unsigned int pk2(float x, float y){
    return ((unsigned)f2b(y) << 16) | (unsigned)f2b(x);
}
__device__ __forceinline__ float b2f(u16 u){
    return __uint_as_float(((unsigned int)u) << 16);
}
__device__ __forceinline__ uint4 pk8(float4 x, float4 y){
    uint4 o;
    o.x = pk2(x.x,x.y); o.y = pk2(x.z,x.w);
    o.z = pk2(y.x,y.y); o.w = pk2(y.z,y.w);
    return o;
}

// ---------------------------------------------------------------------------
// prep: weight preprocessing + zc zero-init (memset folded in).
//  p1W/p2W f32->bf16; qWih/qWhh live-row pack (n'=4d+gate); naW frag blob;
//  bias combine; zc[0..1023] = 0.
// ---------------------------------------------------------------------------
__global__ __launch_bounds__(256) void prep_kernel(
    const float* __restrict__ p1W, const float* __restrict__ p2W,
    const float* __restrict__ naW,
    const float* __restrict__ qWih, const float* __restrict__ qWhh,
    const float* __restrict__ qBih, const float* __restrict__ qBhh,
    u16* __restrict__ p1Wb, u16* __restrict__ p2Wb,
    u16* __restrict__ nawf, u16* __restrict__ WihS, u16* __restrict__ WhhS,
    float* __restrict__ bc, float* __restrict__ zc)
{
    const long gid = (long)blockIdx.x * 256 + threadIdx.x;
    const long E0 = 131072;         // p1W float4 units
    const long E1 = E0 + 131072;    // p2W
    const long E2 = E1 + 131072;    // Wih pack (8 u16/thread)
    const long E3 = E2 + 131072;    // Whh pack
    const long E4 = E3 + 16384;     // naW frag pack
    const long E5 = E4 + 2048;      // bias comb
    const long E6 = E5 + 1024;      // zc zero
    if (gid < E0){
        float4 v = reinterpret_cast<const float4*>(p1W)[gid];
        uint2 s; s.x = pk2(v.x,v.y); s.y = pk2(v.z,v.w);
        reinterpret_cast<uint2*>(p1Wb)[gid] = s;
    } else if (gid < E1){
        long i = gid - E0;
        float4 v = reinterpret_cast<const float4*>(p2W)[i];
        uint2 s; s.x = pk2(v.x,v.y); s.y = pk2(v.z,v.w);
        reinterpret_cast<uint2*>(p2Wb)[i] = s;
    } else if (gid < E2){
        long j = gid - E1;
        int n = (int)(j >> 6), c8 = (int)(j & 63);
        int srow = (n & 3) * 1024 + (n >> 2);
        const float* sp = qWih + (size_t)srow * 512 + c8 * 8;
        float4 a = *reinterpret_cast<const float4*>(sp);
        float4 b = *reinterpret_cast<const float4*>(sp + 4);
        *reinterpret_cast<uint4*>(WihS + (size_t)n*512 + c8*8) = pk8(a,b);
    } else if (gid < E3){
        long j = gid - E2;
        int n = (int)(j >> 6), c8 = (int)(j & 63);
        int srow = (n & 3) * 1024 + (n >> 2);
        const float* sp = qWhh + (size_t)srow * 1024 + c8 * 8;
        float4 a = *reinterpret_cast<const float4*>(sp);
        float4 b = *reinterpret_cast<const float4*>(sp + 4);
        *reinterpret_cast<uint4*>(WhhS + (size_t)n*512 + c8*8) = pk8(a,b);
    } else if (gid < E4){
        long j = gid - E3;                 // 0..16383
        int f = (int)(j >> 6), lane = (int)(j & 63);
        int ks = f >> 4, ig = f & 15;
        int col = lane & 15, quad = lane >> 4;
        int n = ig*16 + col;
        int k0 = ks*32 + quad*8;
        const float* sp = naW + (size_t)n*512 + k0;
        float4 a = *reinterpret_cast<const float4*>(sp);
        float4 b = *reinterpret_cast<const float4*>(sp + 4);
        *reinterpret_cast<uint4*>(nawf + j*8) = pk8(a,b);
    } else if (gid < E5){
        int n = (int)(gid - E4);
        int row = (n & 3) * 1024 + (n >> 2);
        bc[n] = qBih[row] + qBhh[row];
    } else if (gid < E6){
        zc[gid - E5] = 0.f;
    }
}

// ---------------------------------------------------------------------------
// Neighbor encoder v6 (CHAMPION, 117us): one block per (row, side), grid 4102.
// Side-split + ent f32 LDS stash: phase p=1 also copies the gathered f32 ent
// rows into LDS; agg reads LDS instead of re-gathering from global.
// Ledger: v4=138 v5=139 v6=117 v7=145. LDS 49.7KB -> 3 blocks/CU; occupancy
// 21% hurts (v7), 31-74% is time-neutral (v5/v6). FETCH ~123MB = compulsory.
// ---------------------------------------------------------------------------
__global__ __launch_bounds__(256, 3) void neighbor_v6(
    const int* __restrict__ qL, const int* __restrict__ qR,
    const int* __restrict__ sL, const int* __restrict__ sR,
    const float* __restrict__ emb,
    const u16* __restrict__ nawf,
    const float* __restrict__ naB, const float* __restrict__ nuW,
    const float* __restrict__ nuB,
    float* __restrict__ out, u16* __restrict__ out_bf)
{
    __shared__ __align__(16) u16 frg[16*512];     // 16 frags x 1KB
    __shared__ __align__(16) float entf[32*256];  // f32 ent stash (32KB)
    __shared__ int relid[32];
    __shared__ int entid[32];
    __shared__ float logit[32];
    __shared__ float att[32];

    const int t = threadIdx.x;
    const int bx = blockIdx.x;     // 0..4101
    const int row = bx >> 1;       // 0..2050
    const int s = bx & 1;          // side: 0=L 1=R
    if (t < 64){
        int k = t >> 1, which = t & 1;
        const int* conn;
        if (row < 2048) conn = (s ? qR : qL) + (size_t)row * 60;
        else            conn = (s ? sR : sL) + (size_t)(row - 2048) * 60;
        int id = (k < 30) ? conn[k*2 + which] : VPAD;
        if (which) entid[k] = id; else relid[k] = id;
    }
    if (t >= 64 && t < 96) logit[t-64] = 0.f;
    __syncthreads();

    const int w = t >> 6, lane = t & 63;
    const int col = lane & 15, quad = lane >> 4;

    // decode gather unit (constant per thread across phases): 1024 units
    int gc[4], gk[4];
    #pragma unroll
    for (int i = 0; i < 4; i++){
        int idx = i*256 + t;
        gc[i] = idx & 31;            // 8-elem chunk within 256-elem half
        gk[i] = (idx >> 5) & 31;     // row 0..31
    }

    f32x4 acc[2][4] = {};

    #pragma unroll
    for (int p = 0; p < 2; p++){
        // gather phase p (p=0: rel, p=1: ent)
        #pragma unroll
        for (int i = 0; i < 4; i++){
            int k = gk[i], c = gc[i];
            int e0 = c*8;
            int id = p ? entid[k] : relid[k];
            const float* ptr = emb + (size_t)id*256 + e0;
            float4 x = *reinterpret_cast<const float4*>(ptr);
            float4 y = *reinterpret_cast<const float4*>(ptr + 4);
            int ksl = e0 >> 5, q = (e0 >> 3) & 3;
            int mt = k >> 4, cl = k & 15;
            int ln = q*16 + cl;
            u16* dst = frg + (((mt*8 + ksl)*64) + ln)*8;
            *reinterpret_cast<uint4*>(dst) = pk8(x, y);
            if (p){
                float* fd = entf + k*256 + e0;
                *reinterpret_cast<float4*>(fd)     = x;
                *reinterpret_cast<float4*>(fd + 4) = y;
            }
        }
        __syncthreads();

        // MFMA phase: 8 local ks steps
        #pragma unroll
        for (int ksl = 0; ksl < 8; ksl++){
            bf16x8 a[2], b[4];
            #pragma unroll
            for (int u = 0; u < 2; u++)
                a[u] = *reinterpret_cast<const bf16x8*>(frg + (((u*8 + ksl)*64) + lane)*8);
            const int ks = p*8 + ksl;
            #pragma unroll
            for (int i = 0; i < 4; i++)
                b[i] = *reinterpret_cast<const bf16x8*>(nawf + ((size_t)(ks*16 + w*4 + i)*64 + lane)*8);
            #pragma unroll
            for (int i = 0; i < 4; i++)
                #pragma unroll
                for (int u = 0; u < 2; u++)
                    acc[u][i] = MFMA16(a[u], b[i], acc[u][i]);
        }
        __syncthreads();
    }

    // logits
    float nu[4], nbv[4];
    #pragma unroll
    for (int i = 0; i < 4; i++){
        int n = (w*4 + i)*16 + col;
        nu[i] = nuW[n]; nbv[i] = naB[n];
    }
    #pragma unroll
    for (int u = 0; u < 2; u++){
        #pragma unroll
        for (int r = 0; r < 4; r++){
            int m = u*16 + quad*4 + r;
            float v = 0.f;
            #pragma unroll
            for (int i = 0; i < 4; i++)
                v += ftanh(acc[u][i][r] + nbv[i]) * nu[i];
            v += __shfl_xor(v, 1); v += __shfl_xor(v, 2);
            v += __shfl_xor(v, 4); v += __shfl_xor(v, 8);
            if (col == 0 && m < 30) atomicAdd(&logit[m], v);
        }
    }
    __syncthreads();

    if (t == 0){
        const float nub = nuB[0];
        float mx = -1e30f;
        float lg[30];
        #pragma unroll
        for (int k = 0; k < 30; k++){
            float L = logit[k] + nub;
            lg[k] = L; mx = fmaxf(mx, L);
        }
        float sm = 0.f;
        #pragma unroll
        for (int k = 0; k < 30; k++){ float e = __expf(lg[k]-mx); att[k] = e; sm += e; }
        float inv = 1.f / sm;
        #pragma unroll
        for (int k = 0; k < 30; k++) att[k] *= inv;
    }
    __syncthreads();

    // agg: thread t = column e (0..255); ent rows from LDS stash (bit-exact)
    const int e = t;
    float agg = 0.f;
    #pragma unroll
    for (int k = 0; k < 30; k++)
        agg += att[k] * entf[k*256 + e];
    float r = ftanh(agg);
    size_t oi = (size_t)row*512 + s*256 + e;
    out[oi] = r;
    out_bf[oi] = f2b(r);
}

// ---------------------------------------------------------------------------
// gemm_tn: C[m,n] = act( A[m,:]·B[n,:] + bias[n] (+addD[m,n]) )
// A bf16 [M x lda], B bf16 [N x ldb]. 128x64 tile, 4 waves of 64x32.
// BK=128 (was 64): 32 MFMAs per barrier pair instead of 16; K-loop its
// halved (8->4 at K=512). LDS 52KB still allows the grid-capped 2 blocks/CU
// (m132's BK=128 regression was an occupancy 3->2 drop; absent here).
// + T14 register double-buffer (kc+1 issued after LDS write of kc).
// K-accumulation order per output unchanged (ks ascending) -> bit-exact.
// Requires K % 128 == 0 (512, 1024 here).
// ---------------------------------------------------------------------------
__global__ __launch_bounds__(256) void gemm_tn(
    const u16* __restrict__ A, int lda,
    const u16* __restrict__ B, int ldb,
    const float* __restrict__ bias,
    const float* __restrict__ addD, int ldd,
    float* __restrict__ Cf, u16* __restrict__ Cbf, int ldc,
    int K, int relu)
{
    __shared__ __align__(16) u16 As[128][136];
    __shared__ __align__(16) u16 Bs[64][136];
    const int t = threadIdx.x;
    const int m0 = blockIdx.y * 128, n0 = blockIdx.x * 64;
    const int w = t >> 6, lane = t & 63;
    const int col = lane & 15, quad = lane >> 4;
    const int wm = (w & 1) * 64, wn = (w >> 1) * 32;

    // BK=128 staging: A 128x128 u16 = 2048 chunks (8/thread); B 64x128 = 1024 (4/thread)
    int arow[8], aseg[8], brow[4], bseg[4];
    #pragma unroll
    for (int i = 0; i < 8; i++){
        int idx = i*256 + t; arow[i] = idx >> 4; aseg[i] = (idx & 15) * 8;
    }
    #pragma unroll
    for (int i = 0; i < 4; i++){
        int idx = i*256 + t; brow[i] = idx >> 4; bseg[i] = (idx & 15) * 8;
    }

    f32x4 acc[4][2] = {};

    const int KC = K >> 7;
    uint4 av[8], bv[4];
    #pragma unroll
    for (int i = 0; i < 8; i++)
        av[i] = *reinterpret_cast<const uint4*>(A + (size_t)(m0 + arow[i])*lda + aseg[i]);
    #pragma unroll
    for (int i = 0; i < 4; i++)
        bv[i] = *reinterpret_cast<const uint4*>(B + (size_t)(n0 + brow[i])*ldb + bseg[i]);

    for (int kc = 0; kc < KC; kc++){
        __syncthreads();   // prior MFMA done reading LDS
        #pragma unroll
        for (int i = 0; i < 8; i++)
            *reinterpret_cast<uint4*>(&As[arow[i]][aseg[i]]) = av[i];
        #pragma unroll
        for (int i = 0; i < 4; i++)
            *reinterpret_cast<uint4*>(&Bs[brow[i]][bseg[i]]) = bv[i];
        if (kc + 1 < KC){
            #pragma unroll
            for (int i = 0; i < 8; i++)
                av[i] = *reinterpret_cast<const uint4*>(A + (size_t)(m0 + arow[i])*lda + (kc+1)*128 + aseg[i]);
            #pragma unroll
            for (int i = 0; i < 4; i++)
                bv[i] = *reinterpret_cast<const uint4*>(B + (size_t)(n0 + brow[i])*ldb + (kc+1)*128 + bseg[i]);
        }
        __syncthreads();   // LDS tile kc visible to all
        #pragma unroll
        for (int ks = 0; ks < 4; ks++){
            const int k0 = ks*32 + quad*8;
            bf16x8 af[4], bf[2];
            #pragma unroll
            for (int i = 0; i < 4; i++) af[i] = *reinterpret_cast<const bf16x8*>(&As[wm + i*16 + col][k0]);
            #pragma unroll
            for (int j = 0; j < 2; j++) bf[j] = *reinterpret_cast<const bf16x8*>(&Bs[wn + j*16 + col][k0]);
            #pragma unroll
            for (int i = 0; i < 4; i++)
                #pragma unroll
                for (int j = 0; j < 2; j++)
                    acc[i][j] = MFMA16(af[i], bf[j], acc[i][j]);
        }
    }

    #pragma unroll
    for (int j = 0; j < 2; j++){
        int n = n0 + wn + j*16 + col;
        float bj = bias[n];
        #pragma unroll
        for (int i = 0; i < 4; i++){
            #pragma unroll
            for (int r = 0; r < 4; r++){
                int m = m0 + wm + i*16 + quad*4 + r;
                float v = acc[i][j][r] + bj;
                if (addD) v += addD[(size_t)m*ldd + n];
                if (relu) v = fmaxf(v, 0.f);
                if (Cf)  Cf[(size_t)m*ldc + n] = v;
                if (Cbf) Cbf[(size_t)m*ldc + n] = f2b(v);
            }
        }
    }
}

// ---------------------------------------------------------------------------
// LayerNorm(Z + X), ddof=1, eps on sigma. One wave per row; 2051 rows.
// ---------------------------------------------------------------------------
__global__ __launch_bounds__(256) void ln_kernel(
    const float* __restrict__ Z, const float* __restrict__ X, int N, int nquery,
    const float* __restrict__ lnA, const float* __restrict__ lnB,
    float* __restrict__ Y, u16* __restrict__ Ybf, float* __restrict__ Ycopy)
{
    const int wv = threadIdx.x >> 6, lane = threadIdx.x & 63;
    const int row = blockIdx.x * 4 + wv;
    if (row >= N) return;
    const float* z = Z + (size_t)row * 512;
    const float* x = X + (size_t)row * 512;
    float v[8];
    float s = 0.f, ss = 0.f;
    {
        float4 z0 = *reinterpret_cast<const float4*>(z + lane*8);
        float4 z1 = *reinterpret_cast<const float4*>(z + lane*8 + 4);
        float4 x0 = *reinterpret_cast<const float4*>(x + lane*8);
        float4 x1 = *reinterpret_cast<const float4*>(x + lane*8 + 4);
        v[0]=z0.x+x0.x; v[1]=z0.y+x0.y; v[2]=z0.z+x0.z; v[3]=z0.w+x0.w;
        v[4]=z1.x+x1.x; v[5]=z1.y+x1.y; v[6]=z1.z+x1.z; v[7]=z1.w+x1.w;
    }
    #pragma unroll
    for (int u = 0; u < 8; u++){ s += v[u]; ss += v[u]*v[u]; }
    #pragma unroll
    for (int d = 1; d < 64; d <<= 1){
        s  += __shfl_xor(s, d);
        ss += __shfl_xor(ss, d);
    }
    float mu  = s * (1.f/512.f);
    float var = (ss - 512.f*mu*mu) * (1.f/511.f);
    float sd  = sqrtf(fmaxf(var, 0.f));
    float inv = 1.f / (sd + 1e-3f);
    float o[8];
    #pragma unroll
    for (int u = 0; u < 8; u++){
        int e = lane*8 + u;
        o[u] = (v[u] - mu) * inv * lnA[e] + lnB[e];
    }
    float* yr = Y + (size_t)row*512 + lane*8;
    *reinterpret_cast<float4*>(yr)     = make_float4(o[0],o[1],o[2],o[3]);
    *reinterpret_cast<float4*>(yr + 4) = make_float4(o[4],o[5],o[6],o[7]);
    if (row < nquery){
        uint4 p;
        p.x = pk2(o[0],o[1]); p.y = pk2(o[2],o[3]);
        p.z = pk2(o[4],o[5]); p.w = pk2(o[6],o[7]);
        *reinterpret_cast<uint4*>(Ybf + (size_t)row*512 + lane*8) = p;
        float* cr = Ycopy + (size_t)row*512 + lane*8;
        *reinterpret_cast<float4*>(cr)     = make_float4(o[0],o[1],o[2],o[3]);
        *reinterpret_cast<float4*>(cr + 4) = make_float4(o[4],o[5],o[6],o[7]);
    }
}

// ---------------------------------------------------------------------------
// Small LSTM cell (D=512, batch=1): 128 blocks x 4 d, one wave per d
// ---------------------------------------------------------------------------
__global__ __launch_bounds__(256) void lstm_small(
    const float* __restrict__ x, const float* __restrict__ hin,
    float* __restrict__ c,
    const float* __restrict__ Wih, const float* __restrict__ Whh,
    const float* __restrict__ bih, const float* __restrict__ bhh,
    float* __restrict__ hout)
{
    __shared__ float xs[512], hs[512];
    __shared__ float gbuf[4][4];
    const int t = threadIdx.x;
    for (int i = t; i < 512; i += 256){ xs[i] = x[i]; hs[i] = hin[i]; }
    __syncthreads();

    const int wd = t >> 6;
    const int lane = t & 63;
    const int g = lane >> 4, p = lane & 15;
    const int d = blockIdx.x*4 + wd;
    const int j = g*512 + d;
    const float4* wi = reinterpret_cast<const float4*>(Wih + (size_t)j*512) + p*8;
    const float4* wh = reinterpret_cast<const float4*>(Whh + (size_t)j*512) + p*8;
    float acc = 0.f;
    #pragma unroll
    for (int q = 0; q < 8; q++){
        float4 wv = wi[q];
        const int kb = p*32 + q*4;
        acc += xs[kb]*wv.x + xs[kb+1]*wv.y + xs[kb+2]*wv.z + xs[kb+3]*wv.w;
        float4 vv = wh[q];
        acc += hs[kb]*vv.x + hs[kb+1]*vv.y + hs[kb+2]*vv.z + hs[kb+3]*vv.w;
    }
    acc += __shfl_xor(acc, 1); acc += __shfl_xor(acc, 2);
    acc += __shfl_xor(acc, 4); acc += __shfl_xor(acc, 8);
    if (p == 0) gbuf[wd][g] = acc + bih[j] + bhh[j];
    __syncthreads();
    if (t < 4){
        int dd = blockIdx.x*4 + t;
        float iv = gbuf[t][0], fv = gbuf[t][1], gv = gbuf[t][2], ov = gbuf[t][3];
        float cn = sigf(fv)*c[dd] + sigf(iv)*ftanh(gv);
        float hn = sigf(ov)*ftanh(cn);
        c[dd] = cn; hout[dd] = hn;
    }
}

// ---------------------------------------------------------------------------
// wvec + finalize merged: all 8 blocks recompute sge into LDS (bit-identical
// expression); block 0 additionally does ae_loss + outp/sgee global writes.
// ---------------------------------------------------------------------------
__global__ __launch_bounds__(256) void wvec_fin_kernel(
    const float* __restrict__ qWhh,
    const float* __restrict__ sg, const float* __restrict__ enc,
    const float* __restrict__ dec,
    float* __restrict__ sgee, float* __restrict__ wvec,
    float* __restrict__ outp)
{
    __shared__ float ss[512];
    __shared__ float red[4];
    const int t = threadIdx.x;
    #pragma unroll
    for (int u = 0; u < 2; u++){
        int d = u*256 + t;
        float v = sg[d] + enc[d] + sg[512+d] + enc[512+d] + sg[1024+d] + enc[1024+d];
        ss[d] = v;
        if (blockIdx.x == 0){ sgee[d] = v; outp[2049 + d] = v; }
    }
    if (blockIdx.x == 0){
        float s = 0.f;
        for (int i = t; i < 1536; i += 256){ float dd = sg[i] - dec[i]; s += dd*dd; }
        s += __shfl_xor(s,1); s += __shfl_xor(s,2); s += __shfl_xor(s,4);
        s += __shfl_xor(s,8); s += __shfl_xor(s,16); s += __shfl_xor(s,32);
        if ((t & 63) == 0) red[t>>6] = s;
        __syncthreads();
        if (t == 0){
            float tot = (red[0]+red[1]+red[2]+red[3]) * (1.f/1536.f);
            outp[2048] = tot;
        }
    }
    __syncthreads();

    const int n = blockIdx.x * 256 + t;
    const int row = (n & 3) * 1024 + (n >> 2);
    const float4* wq = reinterpret_cast<const float4*>(qWhh + (size_t)row*1024 + 512);
    float acc = 0.f;
    for (int kc = 0; kc < 128; kc++){
        float4 wv = wq[kc];
        const int kb = kc*4;
        acc += ss[kb]*wv.x + ss[kb+1]*wv.y + ss[kb+2]*wv.z + ss[kb+3]*wv.w;
    }
    wvec[n] = acc;
}

// ---------------------------------------------------------------------------
// Gate math on packed G: g4 = (i,f,g,o) at G[b*2048 + 4d]
// first!=0: treat c as 0 (base step) — removes the cb memset + zero-read.
// ---------------------------------------------------------------------------
__global__ __launch_bounds__(256) void gate_kernel(
    const float* __restrict__ G, const float* __restrict__ qg,
    float* __restrict__ c, u16* __restrict__ h_bf, int first)
{
    const int idx = blockIdx.x * 256 + threadIdx.x;
    const int b = idx >> 9, d = idx & 511;
    float4 g4 = *reinterpret_cast<const float4*>(G + (size_t)b*2048 + d*4);
    float c0 = first ? 0.f : c[idx];
    float cn = sigf(g4.y)*c0 + sigf(g4.x)*ftanh(g4.z);
    float hn = qg[idx] + sigf(g4.w)*ftanh(cn);
    c[idx] = cn; h_bf[idx] = f2b(hn);
}

// ---------------------------------------------------------------------------
// matching_scores[b] = dot(h[b], sge_enc)
// ---------------------------------------------------------------------------
__global__ __launch_bounds__(256) void scores_kernel(
    const u16* __restrict__ h, const float* __restrict__ sge,
    float* __restrict__ out)
{
    const int wave = threadIdx.x >> 6, lane = threadIdx.x & 63;
    const int row = blockIdx.x * 4 + wave;
    const u16* hr = h + (size_t)row * 512;
    float s = 0.f;
    for (int i = lane; i < 512; i += 64) s += b2f(hr[i]) * sge[i];
    s += __shfl_xor(s,1); s += __shfl_xor(s,2); s += __shfl_xor(s,4);
    s += __shfl_xor(s,8); s += __shfl_xor(s,16); s += __shfl_xor(s,32);
    if (lane == 0) out[row] = s;
}

// ---------------------------------------------------------------------------
extern "C" void kernel_launch(void* const* d_in, const int* in_sizes, int n_in,
                              void* d_out, int out_size, void* d_ws, size_t ws_size,
                              hipStream_t stream)
{
    (void)in_sizes; (void)n_in; (void)out_size; (void)ws_size;

    const int* qlc = (const int*)d_in[2];
    const int* qrc = (const int*)d_in[4];
    const int* slc = (const int*)d_in[6];
    const int* src = (const int*)d_in[8];
    const float* emb = (const float*)d_in[10];
    const float* naW = (const float*)d_in[11];
    const float* naB = (const float*)d_in[12];
    const float* nuW = (const float*)d_in[13];
    const float* nuB = (const float*)d_in[14];
    const float* p1W = (const float*)d_in[15], *p1b = (const float*)d_in[16];
    const float* p2W = (const float*)d_in[17], *p2b = (const float*)d_in[18];
    const float* lnA = (const float*)d_in[19], *lnB = (const float*)d_in[20];
    const float* eWih = (const float*)d_in[21], *eWhh = (const float*)d_in[22];
    const float* eBih = (const float*)d_in[23], *eBhh = (const float*)d_in[24];
    const float* dWih = (const float*)d_in[25], *dWhh = (const float*)d_in[26];
    const float* dBih = (const float*)d_in[27], *dBhh = (const float*)d_in[28];
    const float* qWih = (const float*)d_in[33], *qWhh = (const float*)d_in[34];
    const float* qBih = (const float*)d_in[35], *qBhh = (const float*)d_in[36];
    float* out = (float*)d_out;

    float* w = (float*)d_ws;
    size_t off = 0;
    auto alloc = [&](size_t nelem){ float* p = w + off; off += nelem; return p; };
    float* qn    = alloc(2176ull*512);   // neighbor f32 (2051 rows used)
    float* qg    = alloc(2176ull*512);   // query_g f32 (+ sg rows 2048..2050)
    float* enc   = alloc(1536);
    float* dec   = alloc(1536);
    float* zc    = alloc(1024);
    float* sgee  = alloc(512);
    float* wv    = alloc(2048);
    float* bc    = alloc(2048);
    float* nawfF = alloc(65536);         // 131072 u16 frag-packed naW
    float* base  = alloc(2048ull*2048);  // + Zq, qn_bf aliases
    float* G     = alloc(2048ull*2048);  // + Hq_bf, qg_bf aliases
    float* cb    = alloc(2048ull*512);
    float* hbfF  = alloc(524288);        // h bf16
    float* p1WbF = alloc(262144);
    float* p2WbF = alloc(262144);
    float* WihSF = alloc(524288);
    float* WhhSF = alloc(524288);

    u16* nawf   = (u16*)nawfF;
    u16* p1Wb   = (u16*)p1WbF;
    u16* p2Wb   = (u16*)p2WbF;
    u16* WihSel = (u16*)WihSF;
    u16* WhhSel = (u16*)WhhSF;
    u16* h_bf   = (u16*)hbfF;
    float* Zq   = base;                       // 2176x512 f32
    u16* qn_bf  = (u16*)(base + 2097152);     // 2176x512 u16
    u16* Hq_bf  = (u16*)G;                    // 2176x1024 u16
    u16* qg_bf  = (u16*)(G + 2097152);        // 2176x512 u16 (2048 used)
    float* sg   = qg + 2048ull*512;
    float* zbuf = zc;
    float* cst  = zc + 512;

    // weight preprocessing + zc zero (memset folded in)
    prep_kernel<<<2124, 256, 0, stream>>>(p1W, p2W, naW, qWih, qWhh, qBih, qBhh,
                                          p1Wb, p2Wb, nawf, WihSel, WhhSel, bc, zc);

    // neighbor encoder: (row, side) blocks — 2051 rows x 2 sides
    neighbor_v6<<<4102, 256, 0, stream>>>(qlc, qrc, slc, src, emb,
                                          nawf, naB, nuW, nuB, qn, qn_bf);

    // support encoder fused over 2051 rows: H=relu(X@p1W^T+b); Z=H@p2W^T+b; LN
    gemm_tn<<<dim3(16,17), 256, 0, stream>>>(qn_bf, 512, p1Wb, 512, p1b, nullptr, 0,
                                             nullptr, Hq_bf, 1024, 512, 1);
    gemm_tn<<<dim3(8,17), 256, 0, stream>>>(Hq_bf, 1024, p2Wb, 1024, p2b, nullptr, 0,
                                            Zq, nullptr, 512, 1024, 0);
    ln_kernel<<<513, 256, 0, stream>>>(Zq, qn, 2051, 2048, lnA, lnB, qg, qg_bf, out + 2561);

    // set autoencoder
    lstm_small<<<128, 256, 0, stream>>>(sg,        zbuf,      cst, eWih, eWhh, eBih, eBhh, enc);
    lstm_small<<<128, 256, 0, stream>>>(sg + 512,  enc,       cst, eWih, eWhh, eBih, eBhh, enc + 512);
    lstm_small<<<128, 256, 0, stream>>>(sg + 1024, enc + 512, cst, eWih, eWhh, eBih, eBhh, enc + 1024);
    lstm_small<<<128, 256, 0, stream>>>(enc + 1024, enc + 1024, cst, dWih, dWhh, dBih, dBhh, dec);
    lstm_small<<<128, 256, 0, stream>>>(dec,        dec,        cst, dWih, dWhh, dBih, dBhh, dec + 512);
    lstm_small<<<128, 256, 0, stream>>>(dec + 512,  dec + 512,  cst, dWih, dWhh, dBih, dBhh, dec + 1024);

    // ae_loss + sge + wvec (merged)
    wvec_fin_kernel<<<8, 256, 0, stream>>>(qWhh, sg, enc, dec, sgee, wv, out);

    // query encoder: base = qg@WihSel^T + bc; 4 steps (live half only)
    gemm_tn<<<dim3(32,16), 256, 0, stream>>>(qg_bf, 512, WihSel, 512, bc, nullptr, 0,
                                             base, nullptr, 2048, 512, 0);
    gate_kernel<<<4096, 256, 0, stream>>>(base, qg, cb, h_bf, 1);
    for (int s = 0; s < 3; s++){
        gemm_tn<<<dim3(32,16), 256, 0, stream>>>(h_bf, 512, WhhSel, 512, wv, base, 2048,
                                                 G, nullptr, 2048, 512, 0);
        gate_kernel<<<4096, 256, 0, stream>>>(G, qg, cb, h_bf, 0);
    }

    scores_kernel<<<512, 256, 0, stream>>>(h_bf, sgee, out);
}